// Round 1
// baseline (441.456 us; speedup 1.0000x reference)
//
#include <hip/hip_runtime.h>
#include <hip/hip_bf16.h>
#include <math.h>

#define NB 4
#define NC 512
#define NN 4096
#define NK 20
#define NCP 128

typedef __bf16 bf16x8 __attribute__((ext_vector_type(8)));
typedef float f32x4 __attribute__((ext_vector_type(4)));
typedef short short8 __attribute__((ext_vector_type(8)));

static __device__ __forceinline__ unsigned short f2bf(float f) {
    unsigned int u = __builtin_bit_cast(unsigned int, f);
    unsigned int r = (u + 0x7FFFu + ((u >> 16) & 1u)) >> 16;
    return (unsigned short)r;
}
static __device__ __forceinline__ float bf2f(unsigned short h) {
    unsigned int u = ((unsigned int)h) << 16;
    return __builtin_bit_cast(float, u);
}
static __device__ __forceinline__ bf16x8 ldbf8(const unsigned short* p) {
    return __builtin_bit_cast(bf16x8, *reinterpret_cast<const short8*>(p));
}

#define MFMA16(a, b, c) __builtin_amdgcn_mfma_f32_16x16x32_bf16(a, b, c, 0, 0, 0)

// ---------------- proj: fp[b][n][d] = sum_c feat[b][c][n]*w[d][c] + bias[d] ----
// Computes O^T = W * F  (A = W [d x c], B = feat [c x n]); writes bf16 fp and fpT.
__global__ __launch_bounds__(256) void proj_kernel(
    const float* __restrict__ feat, const float* __restrict__ w,
    const float* __restrict__ bias, unsigned short* __restrict__ fp,
    unsigned short* __restrict__ fpT)
{
    const int b = blockIdx.y;
    const int n0 = blockIdx.x * 64;
    const int tid = threadIdx.x;
    const int wid = tid >> 6;
    const int lane = tid & 63;
    const int lg = lane >> 4, lr = lane & 15;

    __shared__ unsigned short lds_f[64][40];   // [n][c] bf16, +8 pad

    const float* featb = feat + (size_t)b * NC * NN;

    f32x4 acc[2][4];
    #pragma unroll
    for (int i = 0; i < 2; ++i)
        #pragma unroll
        for (int j = 0; j < 4; ++j) acc[i][j] = (f32x4){0.f, 0.f, 0.f, 0.f};

    for (int c0 = 0; c0 < NC; c0 += 32) {
        __syncthreads();
        #pragma unroll
        for (int r = 0; r < 8; ++r) {
            int idx = r * 256 + tid;
            int cc = idx >> 6, nn = idx & 63;
            lds_f[nn][cc] = f2bf(featb[(size_t)(c0 + cc) * NN + n0 + nn]);
        }
        __syncthreads();
        bf16x8 afr[2];
        #pragma unroll
        for (int dt = 0; dt < 2; ++dt) {
            const float* wr = w + (size_t)(wid * 32 + dt * 16 + lr) * NC + c0 + lg * 8;
            short8 a;
            #pragma unroll
            for (int j = 0; j < 8; ++j) a[j] = (short)f2bf(wr[j]);
            afr[dt] = __builtin_bit_cast(bf16x8, a);
        }
        #pragma unroll
        for (int n1 = 0; n1 < 4; ++n1) {
            bf16x8 bfr = ldbf8(&lds_f[n1 * 16 + lr][lg * 8]);
            #pragma unroll
            for (int dt = 0; dt < 2; ++dt)
                acc[dt][n1] = MFMA16(afr[dt], bfr, acc[dt][n1]);
        }
    }
    #pragma unroll
    for (int dt = 0; dt < 2; ++dt)
        #pragma unroll
        for (int n1 = 0; n1 < 4; ++n1)
            #pragma unroll
            for (int i = 0; i < 4; ++i) {
                int d = wid * 32 + dt * 16 + lg * 4 + i;
                int n = n0 + n1 * 16 + lr;
                unsigned short h = f2bf(acc[dt][n1][i] + bias[d]);
                fp[((size_t)b * NN + n) * NCP + d] = h;
                fpT[((size_t)b * NCP + d) * NN + n] = h;
            }
}

// ---------------- class_term: ct[b][k][d] = sum_n cam[b][k][n]*fp[b][n][d] ----
__global__ __launch_bounds__(128) void ct_kernel(
    const float* __restrict__ cam, const unsigned short* __restrict__ fp,
    float* __restrict__ ct)
{
    const int bid = blockIdx.x;
    const int chunk = bid & 7;          // 8 chunks of 512 n each
    const int bk = bid >> 3;
    const int b = bk / NK, k = bk % NK;
    const int d = threadIdx.x;
    const float* camp = cam + ((size_t)b * NK + k) * NN + chunk * 512;
    const unsigned short* fpp = fp + ((size_t)b * NN + chunk * 512) * NCP + d;
    float acc = 0.f;
    #pragma unroll 4
    for (int n = 0; n < 512; ++n)
        acc += camp[n] * bf2f(fpp[(size_t)n * NCP]);
    atomicAdd(&ct[((size_t)b * NK + k) * NCP + d], acc);
}

// ---------------- attention: pt = softmax(fp fp^T) fp ----------------
// block = 128 threads = 2 waves; each wave owns 16 q-rows. KV tile = 64 keys.
__global__ __launch_bounds__(128) void attn_kernel(
    const unsigned short* __restrict__ fp, const unsigned short* __restrict__ fpT,
    unsigned short* __restrict__ pt)
{
    const int b = blockIdx.y;
    const int wid = threadIdx.x >> 6;
    const int lane = threadIdx.x & 63;
    const int lg = lane >> 4, lr = lane & 15;
    const int q0 = blockIdx.x * 32 + wid * 16;

    __shared__ unsigned short p_lds_all[2][16][72];   // per-wave P buffer, +8 pad
    unsigned short (*p_lds)[72] = p_lds_all[wid];

    const unsigned short* fpb  = fp  + (size_t)b * NN * NCP;
    const unsigned short* fpTb = fpT + (size_t)b * NCP * NN;

    // Q fragments (A operand), rows q0..q0+15, K = 128 in 4 chunks of 32
    bf16x8 qf[4];
    #pragma unroll
    for (int kk = 0; kk < 4; ++kk)
        qf[kk] = ldbf8(&fpb[(size_t)(q0 + lr) * NCP + kk * 32 + lg * 8]);

    f32x4 o[8];
    #pragma unroll
    for (int i = 0; i < 8; ++i) o[i] = (f32x4){0.f, 0.f, 0.f, 0.f};
    float m_i[4], l_i[4];
    #pragma unroll
    for (int i = 0; i < 4; ++i) { m_i[i] = -INFINITY; l_i[i] = 0.f; }

    for (int t = 0; t < NN / 64; ++t) {
        const int kv0 = t * 64;
        // S = Q K^T : 4 col-tiles of 16 keys
        f32x4 s[4];
        #pragma unroll
        for (int c = 0; c < 4; ++c) s[c] = (f32x4){0.f, 0.f, 0.f, 0.f};
        #pragma unroll
        for (int kk = 0; kk < 4; ++kk) {
            #pragma unroll
            for (int c = 0; c < 4; ++c) {
                bf16x8 kf = ldbf8(&fpb[(size_t)(kv0 + c * 16 + lr) * NCP + kk * 32 + lg * 8]);
                s[c] = MFMA16(qf[kk], kf, s[c]);
            }
        }
        // online softmax: rows live at (lg*4+i), cols at lr across the 16-lane group
        float sc[4];
        #pragma unroll
        for (int i = 0; i < 4; ++i) {
            float v = fmaxf(fmaxf(s[0][i], s[1][i]), fmaxf(s[2][i], s[3][i]));
            v = fmaxf(v, __shfl_xor(v, 1));
            v = fmaxf(v, __shfl_xor(v, 2));
            v = fmaxf(v, __shfl_xor(v, 4));
            v = fmaxf(v, __shfl_xor(v, 8));
            float mnew = fmaxf(m_i[i], v);
            sc[i] = __expf(m_i[i] - mnew);
            float sum = 0.f;
            #pragma unroll
            for (int c = 0; c < 4; ++c) {
                float p = __expf(s[c][i] - mnew);
                s[c][i] = p;
                sum += p;
            }
            sum += __shfl_xor(sum, 1);
            sum += __shfl_xor(sum, 2);
            sum += __shfl_xor(sum, 4);
            sum += __shfl_xor(sum, 8);
            l_i[i] = l_i[i] * sc[i] + sum;
            m_i[i] = mnew;
        }
        #pragma unroll
        for (int d0 = 0; d0 < 8; ++d0)
            #pragma unroll
            for (int i = 0; i < 4; ++i) o[d0][i] *= sc[i];
        // P (D-layout) -> LDS -> A-fragment layout
        #pragma unroll
        for (int c = 0; c < 4; ++c)
            #pragma unroll
            for (int i = 0; i < 4; ++i)
                p_lds[lg * 4 + i][c * 16 + lr] = f2bf(s[c][i]);
        asm volatile("s_waitcnt lgkmcnt(0)" ::: "memory");
        bf16x8 pa[2];
        #pragma unroll
        for (int kk2 = 0; kk2 < 2; ++kk2)
            pa[kk2] = ldbf8(&p_lds[lr][kk2 * 32 + lg * 8]);
        // O += P V : B operand read from fpT (contiguous 16B rows)
        #pragma unroll
        for (int kk2 = 0; kk2 < 2; ++kk2) {
            #pragma unroll
            for (int d0 = 0; d0 < 8; ++d0) {
                bf16x8 vf = ldbf8(&fpTb[(size_t)(d0 * 16 + lr) * NN + kv0 + kk2 * 32 + lg * 8]);
                o[d0] = MFMA16(pa[kk2], vf, o[d0]);
            }
        }
    }
    #pragma unroll
    for (int d0 = 0; d0 < 8; ++d0)
        #pragma unroll
        for (int i = 0; i < 4; ++i) {
            float v = o[d0][i] / l_i[i];
            pt[((size_t)b * NN + q0 + lg * 4 + i) * NCP + d0 * 16 + lr] = f2bf(v);
        }
}

// ---------------- aug: out[b][k][n] = cam + sum_d ct[b][k][d]*pt[b][n][d] ----
__global__ __launch_bounds__(64) void aug_kernel(
    const float* __restrict__ cam, const float* __restrict__ ct,
    const unsigned short* __restrict__ pt, float* __restrict__ out)
{
    const int b = blockIdx.y;
    const int n = blockIdx.x * 64 + threadIdx.x;
    __shared__ float ct_s[NK][NCP];
    for (int i = threadIdx.x; i < NK * NCP; i += 64)
        ct_s[i >> 7][i & 127] = ct[(size_t)b * NK * NCP + i];
    __syncthreads();
    short8 ptv[16];
    const short8* pp = reinterpret_cast<const short8*>(pt + ((size_t)b * NN + n) * NCP);
    #pragma unroll
    for (int i = 0; i < 16; ++i) ptv[i] = pp[i];
    for (int k = 0; k < NK; ++k) {
        float acc = 0.f;
        #pragma unroll
        for (int v8 = 0; v8 < 16; ++v8) {
            short8 x = ptv[v8];
            #pragma unroll
            for (int j = 0; j < 8; ++j)
                acc += ct_s[k][v8 * 8 + j] * bf2f((unsigned short)x[j]);
        }
        size_t off = ((size_t)b * NK + k) * NN + n;
        out[off] = cam[off] + acc;
    }
}

extern "C" void kernel_launch(void* const* d_in, const int* in_sizes, int n_in,
                              void* d_out, int out_size, void* d_ws, size_t ws_size,
                              hipStream_t stream) {
    const float* feat = (const float*)d_in[0];
    const float* cam  = (const float*)d_in[1];
    const float* wpr  = (const float*)d_in[2];
    const float* bpr  = (const float*)d_in[3];
    float* out = (float*)d_out;

    char* ws = (char*)d_ws;
    unsigned short* fp  = (unsigned short*)(ws);                               // 4 MB
    unsigned short* fpT = (unsigned short*)(ws + (size_t)4 * 1024 * 1024);     // 4 MB
    unsigned short* pt  = (unsigned short*)(ws + (size_t)8 * 1024 * 1024);     // 4 MB
    float* ct           = (float*)(ws + (size_t)12 * 1024 * 1024);             // 40 KB

    hipMemsetAsync(ct, 0, (size_t)NB * NK * NCP * sizeof(float), stream);
    proj_kernel<<<dim3(NN / 64, NB), 256, 0, stream>>>(feat, wpr, bpr, fp, fpT);
    ct_kernel<<<NB * NK * 8, 128, 0, stream>>>(cam, fp, ct);
    attn_kernel<<<dim3(NN / 32, NB), 128, 0, stream>>>(fp, fpT, pt);
    aug_kernel<<<dim3(NN / 64, NB), 64, 0, stream>>>(cam, ct, pt, out);
}

// Round 2
// 205.669 us; speedup vs baseline: 2.1464x; 2.1464x over previous
//
#include <hip/hip_runtime.h>
#include <hip/hip_bf16.h>
#include <math.h>

#define NB 4
#define NC 512
#define NN 4096
#define NK 20
#define NCP 128
#define SPLIT 4
#define CHUNK (NN / SPLIT)   // 1024 keys per split

typedef __bf16 bf16x8 __attribute__((ext_vector_type(8)));
typedef float f32x4 __attribute__((ext_vector_type(4)));
typedef short short8 __attribute__((ext_vector_type(8)));

static __device__ __forceinline__ unsigned short f2bf(float f) {
    unsigned int u = __builtin_bit_cast(unsigned int, f);
    unsigned int r = (u + 0x7FFFu + ((u >> 16) & 1u)) >> 16;
    return (unsigned short)r;
}
static __device__ __forceinline__ float bf2f(unsigned short h) {
    unsigned int u = ((unsigned int)h) << 16;
    return __builtin_bit_cast(float, u);
}
static __device__ __forceinline__ bf16x8 ldbf8(const unsigned short* p) {
    return __builtin_bit_cast(bf16x8, *reinterpret_cast<const short8*>(p));
}
// async global->LDS, 16B per lane. LDS dest must be wave-uniform base.
static __device__ __forceinline__ void gld16(const unsigned short* g, unsigned short* l) {
    __builtin_amdgcn_global_load_lds(
        (const __attribute__((address_space(1))) unsigned int*)g,
        (__attribute__((address_space(3))) unsigned int*)l, 16, 0, 0);
}

#define MFMA16(a, b, c) __builtin_amdgcn_mfma_f32_16x16x32_bf16(a, b, c, 0, 0, 0)

// ---------------- proj: fp[b][n][d] = sum_c feat[b][c][n]*w[d][c] + bias[d] ----
__global__ __launch_bounds__(256) void proj_kernel(
    const float* __restrict__ feat, const float* __restrict__ w,
    const float* __restrict__ bias, unsigned short* __restrict__ fp,
    unsigned short* __restrict__ fpT)
{
    const int b = blockIdx.y;
    const int n0 = blockIdx.x * 64;
    const int tid = threadIdx.x;
    const int wid = tid >> 6;
    const int lane = tid & 63;
    const int lg = lane >> 4, lr = lane & 15;

    __shared__ unsigned short lds_f[64][40];   // [n][c] bf16, +8 pad

    const float* featb = feat + (size_t)b * NC * NN;

    f32x4 acc[2][4];
    #pragma unroll
    for (int i = 0; i < 2; ++i)
        #pragma unroll
        for (int j = 0; j < 4; ++j) acc[i][j] = (f32x4){0.f, 0.f, 0.f, 0.f};

    for (int c0 = 0; c0 < NC; c0 += 32) {
        __syncthreads();
        #pragma unroll
        for (int r = 0; r < 8; ++r) {
            int idx = r * 256 + tid;
            int cc = idx >> 6, nn = idx & 63;
            lds_f[nn][cc] = f2bf(featb[(size_t)(c0 + cc) * NN + n0 + nn]);
        }
        __syncthreads();
        bf16x8 afr[2];
        #pragma unroll
        for (int dt = 0; dt < 2; ++dt) {
            const float* wr = w + (size_t)(wid * 32 + dt * 16 + lr) * NC + c0 + lg * 8;
            short8 a;
            #pragma unroll
            for (int j = 0; j < 8; ++j) a[j] = (short)f2bf(wr[j]);
            afr[dt] = __builtin_bit_cast(bf16x8, a);
        }
        #pragma unroll
        for (int n1 = 0; n1 < 4; ++n1) {
            bf16x8 bfr = ldbf8(&lds_f[n1 * 16 + lr][lg * 8]);
            #pragma unroll
            for (int dt = 0; dt < 2; ++dt)
                acc[dt][n1] = MFMA16(afr[dt], bfr, acc[dt][n1]);
        }
    }
    #pragma unroll
    for (int dt = 0; dt < 2; ++dt)
        #pragma unroll
        for (int n1 = 0; n1 < 4; ++n1)
            #pragma unroll
            for (int i = 0; i < 4; ++i) {
                int d = wid * 32 + dt * 16 + lg * 4 + i;
                int n = n0 + n1 * 16 + lr;
                unsigned short h = f2bf(acc[dt][n1][i] + bias[d]);
                fp[((size_t)b * NN + n) * NCP + d] = h;
                fpT[((size_t)b * NCP + d) * NN + n] = h;
            }
}

// ---------------- class_term: ct[b][k][d] = sum_n cam[b][k][n]*fp[b][n][d] ----
__global__ __launch_bounds__(128) void ct_kernel(
    const float* __restrict__ cam, const unsigned short* __restrict__ fp,
    float* __restrict__ ct)
{
    const int bid = blockIdx.x;
    const int chunk = bid & 7;
    const int bk = bid >> 3;
    const int b = bk / NK, k = bk % NK;
    const int d = threadIdx.x;
    const float* camp = cam + ((size_t)b * NK + k) * NN + chunk * 512;
    const unsigned short* fpp = fp + ((size_t)b * NN + chunk * 512) * NCP + d;
    float acc = 0.f;
    #pragma unroll 4
    for (int n = 0; n < 512; ++n)
        acc += camp[n] * bf2f(fpp[(size_t)n * NCP]);
    atomicAdd(&ct[((size_t)b * NK + k) * NCP + d], acc);
}

// ---------------- attention partials over a 1024-key chunk ----------------
// block = 256 threads = 4 waves; wave owns 16 q-rows; KV tile = 64 keys staged
// in LDS (XOR-swizzled via pre-swizzled global source, linear global_load_lds).
__global__ __launch_bounds__(256, 3) void attn_partial_kernel(
    const unsigned short* __restrict__ fp, const unsigned short* __restrict__ fpT,
    float* __restrict__ po, float* __restrict__ mbuf, float* __restrict__ lbuf)
{
    const int b = blockIdx.z;
    const int sidx = blockIdx.y;
    const int tid = threadIdx.x;
    const int wid = tid >> 6;
    const int lane = tid & 63;
    const int lg = lane >> 4, lr = lane & 15;
    const int q0 = blockIdx.x * 64 + wid * 16;
    const int kvbase = sidx * CHUNK;

    __shared__ unsigned short kt[64 * 128];          // K tile [64 keys][128 d], 16B-chunk-swizzled
    __shared__ unsigned short vt[128 * 64];          // V tile [128 d][64 kv],  16B-chunk-swizzled
    __shared__ unsigned short p_lds_all[4][16][72];  // per-wave P buffer
    unsigned short (*p_lds)[72] = p_lds_all[wid];

    const unsigned short* fpb  = fp  + (size_t)b * NN * NCP;
    const unsigned short* fpTb = fpT + (size_t)b * NCP * NN;

    bf16x8 qf[4];
    #pragma unroll
    for (int kk = 0; kk < 4; ++kk)
        qf[kk] = ldbf8(&fpb[(size_t)(q0 + lr) * NCP + kk * 32 + lg * 8]);

    f32x4 o[8];
    #pragma unroll
    for (int i = 0; i < 8; ++i) o[i] = (f32x4){0.f, 0.f, 0.f, 0.f};
    float m_i[4], l_i[4];
    #pragma unroll
    for (int i = 0; i < 4; ++i) { m_i[i] = -INFINITY; l_i[i] = 0.f; }

    for (int t = 0; t < CHUNK / 64; ++t) {
        const int kv0 = kvbase + t * 64;
        __syncthreads();   // everyone done reading previous tile
        // stage K: 1024 chunks of 16B; LDS chunk c holds global chunk c^(r&7)
        #pragma unroll
        for (int i = 0; i < 4; ++i) {
            int oc = i * 256 + tid;
            int r = oc >> 4, c = oc & 15;
            gld16(&fpb[(size_t)(kv0 + r) * NCP + ((c ^ (r & 7)) << 3)],
                  &kt[(size_t)(i * 256 + wid * 64) * 8]);
        }
        // stage V (fpT layout): rows d=0..127, 8 chunks each
        #pragma unroll
        for (int i = 0; i < 4; ++i) {
            int oc = i * 256 + tid;
            int r = oc >> 3, c = oc & 7;
            gld16(&fpTb[(size_t)r * NN + kv0 + ((c ^ (r & 7)) << 3)],
                  &vt[(size_t)(i * 256 + wid * 64) * 8]);
        }
        __syncthreads();   // drains vmcnt -> LDS ready

        // S = Q K^T
        f32x4 s[4];
        #pragma unroll
        for (int c = 0; c < 4; ++c) s[c] = (f32x4){0.f, 0.f, 0.f, 0.f};
        #pragma unroll
        for (int kk = 0; kk < 4; ++kk) {
            #pragma unroll
            for (int c = 0; c < 4; ++c) {
                int rk = c * 16 + lr;
                bf16x8 kf = ldbf8(&kt[rk * 128 + (((kk * 4 + lg) ^ (rk & 7)) << 3)]);
                s[c] = MFMA16(qf[kk], kf, s[c]);
            }
        }
        // online softmax
        float sc[4];
        #pragma unroll
        for (int i = 0; i < 4; ++i) {
            float v = fmaxf(fmaxf(s[0][i], s[1][i]), fmaxf(s[2][i], s[3][i]));
            v = fmaxf(v, __shfl_xor(v, 1));
            v = fmaxf(v, __shfl_xor(v, 2));
            v = fmaxf(v, __shfl_xor(v, 4));
            v = fmaxf(v, __shfl_xor(v, 8));
            float mnew = fmaxf(m_i[i], v);
            sc[i] = __expf(m_i[i] - mnew);
            float sum = 0.f;
            #pragma unroll
            for (int c = 0; c < 4; ++c) {
                float p = __expf(s[c][i] - mnew);
                s[c][i] = p;
                sum += p;
            }
            sum += __shfl_xor(sum, 1);
            sum += __shfl_xor(sum, 2);
            sum += __shfl_xor(sum, 4);
            sum += __shfl_xor(sum, 8);
            l_i[i] = l_i[i] * sc[i] + sum;
            m_i[i] = mnew;
        }
        #pragma unroll
        for (int d0 = 0; d0 < 8; ++d0)
            #pragma unroll
            for (int i = 0; i < 4; ++i) o[d0][i] *= sc[i];
        // P (D-layout) -> LDS -> A-fragment layout
        #pragma unroll
        for (int c = 0; c < 4; ++c)
            #pragma unroll
            for (int i = 0; i < 4; ++i)
                p_lds[lg * 4 + i][c * 16 + lr] = f2bf(s[c][i]);
        asm volatile("s_waitcnt lgkmcnt(0)" ::: "memory");
        bf16x8 pa[2];
        #pragma unroll
        for (int kk2 = 0; kk2 < 2; ++kk2)
            pa[kk2] = ldbf8(&p_lds[lr][kk2 * 32 + lg * 8]);
        // O += P V
        #pragma unroll
        for (int kk2 = 0; kk2 < 2; ++kk2) {
            #pragma unroll
            for (int d0 = 0; d0 < 8; ++d0) {
                int rv = d0 * 16 + lr;
                bf16x8 vf = ldbf8(&vt[rv * 64 + (((kk2 * 4 + lg) ^ (rv & 7)) << 3)]);
                o[d0] = MFMA16(pa[kk2], vf, o[d0]);
            }
        }
    }
    // write unnormalized partials
    const size_t pbase = (size_t)(b * SPLIT + sidx) * NN + q0;
    #pragma unroll
    for (int d0 = 0; d0 < 8; ++d0)
        #pragma unroll
        for (int i = 0; i < 4; ++i)
            po[(pbase + lg * 4 + i) * NCP + d0 * 16 + lr] = o[d0][i];
    if (lr == 0) {
        #pragma unroll
        for (int i = 0; i < 4; ++i) {
            mbuf[pbase + lg * 4 + i] = m_i[i];
            lbuf[pbase + lg * 4 + i] = l_i[i];
        }
    }
}

// ---------------- merge partials -> pt (bf16) ----------------
__global__ __launch_bounds__(64) void merge_kernel(
    const float* __restrict__ po, const float* __restrict__ mbuf,
    const float* __restrict__ lbuf, unsigned short* __restrict__ pt)
{
    const int b = blockIdx.y, n = blockIdx.x;
    const int lane = threadIdx.x;
    float m_s[SPLIT], l_s[SPLIT];
    float M = -INFINITY;
    #pragma unroll
    for (int s = 0; s < SPLIT; ++s) {
        m_s[s] = mbuf[(size_t)(b * SPLIT + s) * NN + n];
        l_s[s] = lbuf[(size_t)(b * SPLIT + s) * NN + n];
        M = fmaxf(M, m_s[s]);
    }
    float L = 0.f, wgt[SPLIT];
    #pragma unroll
    for (int s = 0; s < SPLIT; ++s) { wgt[s] = __expf(m_s[s] - M); L += wgt[s] * l_s[s]; }
    const float inv = 1.f / L;
    float ax = 0.f, ay = 0.f;
    #pragma unroll
    for (int s = 0; s < SPLIT; ++s) {
        const float2* row = (const float2*)(po + ((size_t)(b * SPLIT + s) * NN + n) * NCP);
        float2 v = row[lane];
        ax += wgt[s] * v.x;
        ay += wgt[s] * v.y;
    }
    unsigned short* dst = pt + ((size_t)b * NN + n) * NCP + lane * 2;
    dst[0] = f2bf(ax * inv);
    dst[1] = f2bf(ay * inv);
}

// ---------------- aug: out[b][k][n] = cam + sum_d ct[b][k][d]*pt[b][n][d] ----
__global__ __launch_bounds__(64) void aug_kernel(
    const float* __restrict__ cam, const float* __restrict__ ct,
    const unsigned short* __restrict__ pt, float* __restrict__ out)
{
    const int b = blockIdx.y;
    const int n = blockIdx.x * 64 + threadIdx.x;
    __shared__ float ct_s[NK][NCP];
    for (int i = threadIdx.x; i < NK * NCP; i += 64)
        ct_s[i >> 7][i & 127] = ct[(size_t)b * NK * NCP + i];
    __syncthreads();
    short8 ptv[16];
    const short8* pp = reinterpret_cast<const short8*>(pt + ((size_t)b * NN + n) * NCP);
    #pragma unroll
    for (int i = 0; i < 16; ++i) ptv[i] = pp[i];
    for (int k = 0; k < NK; ++k) {
        float acc = 0.f;
        #pragma unroll
        for (int v8 = 0; v8 < 16; ++v8) {
            short8 x = ptv[v8];
            #pragma unroll
            for (int j = 0; j < 8; ++j)
                acc += ct_s[k][v8 * 8 + j] * bf2f((unsigned short)x[j]);
        }
        size_t off = ((size_t)b * NK + k) * NN + n;
        out[off] = cam[off] + acc;
    }
}

extern "C" void kernel_launch(void* const* d_in, const int* in_sizes, int n_in,
                              void* d_out, int out_size, void* d_ws, size_t ws_size,
                              hipStream_t stream) {
    const float* feat = (const float*)d_in[0];
    const float* cam  = (const float*)d_in[1];
    const float* wpr  = (const float*)d_in[2];
    const float* bpr  = (const float*)d_in[3];
    float* out = (float*)d_out;

    const size_t MB = 1024 * 1024;
    char* ws = (char*)d_ws;
    unsigned short* fp  = (unsigned short*)(ws);             // 4 MB
    unsigned short* fpT = (unsigned short*)(ws + 4 * MB);    // 4 MB
    unsigned short* pt  = (unsigned short*)(ws + 8 * MB);    // 4 MB
    float* ct           = (float*)(ws + 12 * MB);            // 40 KB
    float* po           = (float*)(ws + 13 * MB);            // 32 MB fp32 partial O
    float* mbuf         = (float*)(ws + 45 * MB);            // 256 KB
    float* lbuf         = (float*)(ws + 46 * MB);            // 256 KB

    hipMemsetAsync(ct, 0, (size_t)NB * NK * NCP * sizeof(float), stream);
    proj_kernel<<<dim3(NN / 64, NB), 256, 0, stream>>>(feat, wpr, bpr, fp, fpT);
    ct_kernel<<<NB * NK * 8, 128, 0, stream>>>(cam, fp, ct);
    attn_partial_kernel<<<dim3(NN / 64, SPLIT, NB), 256, 0, stream>>>(fp, fpT, po, mbuf, lbuf);
    merge_kernel<<<dim3(NN, NB), 64, 0, stream>>>(po, mbuf, lbuf, pt);
    aug_kernel<<<dim3(NN / 64, NB), 64, 0, stream>>>(cam, ct, pt, out);
}

// Round 3
// 126.808 us; speedup vs baseline: 3.4813x; 1.6219x over previous
//
#include <hip/hip_runtime.h>
#include <hip/hip_bf16.h>
#include <math.h>

#define NB 4
#define NC 512
#define NN 4096
#define NK 20
#define NCP 128
#define SPLIT 4
#define CHUNK (NN / SPLIT)   // 1024 keys per split
#define NTILES (CHUNK / 64)  // 16

typedef __bf16 bf16x8 __attribute__((ext_vector_type(8)));
typedef float f32x4 __attribute__((ext_vector_type(4)));
typedef short short8 __attribute__((ext_vector_type(8)));

static __device__ __forceinline__ unsigned short f2bf(float f) {
    unsigned int u = __builtin_bit_cast(unsigned int, f);
    unsigned int r = (u + 0x7FFFu + ((u >> 16) & 1u)) >> 16;
    return (unsigned short)r;
}
static __device__ __forceinline__ float bf2f(unsigned short h) {
    unsigned int u = ((unsigned int)h) << 16;
    return __builtin_bit_cast(float, u);
}
static __device__ __forceinline__ bf16x8 ldbf8(const unsigned short* p) {
    return __builtin_bit_cast(bf16x8, *reinterpret_cast<const short8*>(p));
}
static __device__ __forceinline__ void gld16(const unsigned short* g, unsigned short* l) {
    __builtin_amdgcn_global_load_lds(
        (const __attribute__((address_space(1))) unsigned int*)g,
        (__attribute__((address_space(3))) unsigned int*)l, 16, 0, 0);
}

#define MFMA16(a, b, c) __builtin_amdgcn_mfma_f32_16x16x32_bf16(a, b, c, 0, 0, 0)
#define SCHED0() __builtin_amdgcn_sched_barrier(0)
#define BAR() do { SCHED0(); __builtin_amdgcn_s_barrier(); SCHED0(); } while (0)

// ---------------- proj: fp[b][n][d] = sum_c feat[b][c][n]*w[d][c] + bias[d] ----
__global__ __launch_bounds__(256) void proj_kernel(
    const float* __restrict__ feat, const float* __restrict__ w,
    const float* __restrict__ bias, unsigned short* __restrict__ fp,
    unsigned short* __restrict__ fpT)
{
    const int b = blockIdx.y;
    const int n0 = blockIdx.x * 64;
    const int tid = threadIdx.x;
    const int wid = tid >> 6;
    const int lane = tid & 63;
    const int lg = lane >> 4, lr = lane & 15;

    __shared__ unsigned short lds_f[64][40];   // [n][c] bf16, +8 pad

    const float* featb = feat + (size_t)b * NC * NN;

    f32x4 acc[2][4];
    #pragma unroll
    for (int i = 0; i < 2; ++i)
        #pragma unroll
        for (int j = 0; j < 4; ++j) acc[i][j] = (f32x4){0.f, 0.f, 0.f, 0.f};

    for (int c0 = 0; c0 < NC; c0 += 32) {
        __syncthreads();
        #pragma unroll
        for (int it = 0; it < 2; ++it) {
            int idx = it * 256 + tid;          // 0..511
            int cc = idx >> 4, q = idx & 15;
            float4 v = *reinterpret_cast<const float4*>(
                &featb[(size_t)(c0 + cc) * NN + n0 + q * 4]);
            lds_f[q * 4 + 0][cc] = f2bf(v.x);
            lds_f[q * 4 + 1][cc] = f2bf(v.y);
            lds_f[q * 4 + 2][cc] = f2bf(v.z);
            lds_f[q * 4 + 3][cc] = f2bf(v.w);
        }
        __syncthreads();
        bf16x8 afr[2];
        #pragma unroll
        for (int dt = 0; dt < 2; ++dt) {
            const float4* wr = reinterpret_cast<const float4*>(
                w + (size_t)(wid * 32 + dt * 16 + lr) * NC + c0 + lg * 8);
            float4 w0 = wr[0], w1 = wr[1];
            short8 a;
            a[0] = (short)f2bf(w0.x); a[1] = (short)f2bf(w0.y);
            a[2] = (short)f2bf(w0.z); a[3] = (short)f2bf(w0.w);
            a[4] = (short)f2bf(w1.x); a[5] = (short)f2bf(w1.y);
            a[6] = (short)f2bf(w1.z); a[7] = (short)f2bf(w1.w);
            afr[dt] = __builtin_bit_cast(bf16x8, a);
        }
        #pragma unroll
        for (int n1 = 0; n1 < 4; ++n1) {
            bf16x8 bfr = ldbf8(&lds_f[n1 * 16 + lr][lg * 8]);
            #pragma unroll
            for (int dt = 0; dt < 2; ++dt)
                acc[dt][n1] = MFMA16(afr[dt], bfr, acc[dt][n1]);
        }
    }
    #pragma unroll
    for (int dt = 0; dt < 2; ++dt)
        #pragma unroll
        for (int n1 = 0; n1 < 4; ++n1)
            #pragma unroll
            for (int i = 0; i < 4; ++i) {
                int d = wid * 32 + dt * 16 + lg * 4 + i;
                int n = n0 + n1 * 16 + lr;
                unsigned short h = f2bf(acc[dt][n1][i] + bias[d]);
                fp[((size_t)b * NN + n) * NCP + d] = h;
                fpT[((size_t)b * NCP + d) * NN + n] = h;
            }
}

// ---------------- class_term: ct[b][k][d] = sum_n cam[b][k][n]*fp[b][n][d] ----
__global__ __launch_bounds__(128) void ct_kernel(
    const float* __restrict__ cam, const unsigned short* __restrict__ fp,
    float* __restrict__ ct)
{
    const int bid = blockIdx.x;
    const int chunk = bid & 15;         // 16 chunks of 256 n
    const int bk = bid >> 4;
    const int b = bk / NK, k = bk % NK;
    const int d = threadIdx.x;
    const float* camp = cam + ((size_t)b * NK + k) * NN + chunk * 256;
    const unsigned short* fpp = fp + ((size_t)b * NN + chunk * 256) * NCP + d;
    float acc = 0.f;
    #pragma unroll 8
    for (int n = 0; n < 256; ++n)
        acc += camp[n] * bf2f(fpp[(size_t)n * NCP]);
    atomicAdd(&ct[((size_t)b * NK + k) * NCP + d], acc);
}

// ---------------- attention partials over a 1024-key chunk ----------------
// 512 threads = 8 waves; wave owns 16 q-rows (block = 128 q).
// Pipeline per tile: issue V -> QK^T -> softmax -> issue K[t+1] ->
// vmcnt(2) (V ready, K in flight) -> bar -> PV -> vmcnt(0) -> bar.
__global__ __launch_bounds__(512, 4) void attn_partial_kernel(
    const unsigned short* __restrict__ fp, const unsigned short* __restrict__ fpT,
    float* __restrict__ po, float* __restrict__ mbuf, float* __restrict__ lbuf)
{
    const int b = blockIdx.z;
    const int sidx = blockIdx.y;
    const int tid = threadIdx.x;
    const int wid = tid >> 6;
    const int lane = tid & 63;
    const int lg = lane >> 4, lr = lane & 15;
    const int q0 = blockIdx.x * 128 + wid * 16;
    const int kvbase = sidx * CHUNK;

    __shared__ unsigned short kt[2][64 * 128];       // K dbuf, 16B-chunk swizzled
    __shared__ unsigned short vt[128 * 64];          // V single buf, swizzled
    __shared__ unsigned short p_lds_all[8][16][72];
    unsigned short (*p_lds)[72] = p_lds_all[wid];

    const unsigned short* fpb  = fp  + (size_t)b * NN * NCP;
    const unsigned short* fpTb = fpT + (size_t)b * NCP * NN;

    // per-lane swizzled staging offsets (hoisted out of loop)
    int offK[2], offV[2];
    #pragma unroll
    for (int i = 0; i < 2; ++i) {
        int slot = wid * 128 + i * 64 + lane;
        int rk = slot >> 4, ck = slot & 15;
        offK[i] = rk * NCP + ((ck ^ (rk & 7)) << 3);
        int rv = slot >> 3, cv = slot & 7;
        offV[i] = rv * NN + ((cv ^ (rv & 7)) << 3);
    }
    unsigned short* ktw0[2] = { &kt[0][(wid * 128) * 8], &kt[1][(wid * 128) * 8] };
    unsigned short* vtw0 = &vt[(wid * 128) * 8];

    bf16x8 qf[4];
    #pragma unroll
    for (int kk = 0; kk < 4; ++kk)
        qf[kk] = ldbf8(&fpb[(size_t)(q0 + lr) * NCP + kk * 32 + lg * 8]);

    f32x4 o[8];
    #pragma unroll
    for (int i = 0; i < 8; ++i) o[i] = (f32x4){0.f, 0.f, 0.f, 0.f};
    float m_i[4], l_i[4];
    #pragma unroll
    for (int i = 0; i < 4; ++i) { m_i[i] = -INFINITY; l_i[i] = 0.f; }

    // prologue: stage K[0]
    {
        const unsigned short* k0 = fpb + (size_t)kvbase * NCP;
        gld16(k0 + offK[0], ktw0[0]);
        gld16(k0 + offK[1], ktw0[0] + 64 * 8);
    }
    SCHED0();
    asm volatile("s_waitcnt vmcnt(0)" ::: "memory");
    BAR();

    const unsigned short* vsrc = fpTb + kvbase;

    for (int t = 0; t < NTILES; ++t) {
        const int cur = t & 1;
        // ---- issue V[t] stage ----
        gld16(vsrc + offV[0], vtw0);
        gld16(vsrc + offV[1], vtw0 + 64 * 8);
        SCHED0();
        // ---- QK^T from kt[cur] ----
        const unsigned short* ktc = &kt[cur][0];
        f32x4 s[4];
        #pragma unroll
        for (int c = 0; c < 4; ++c) s[c] = (f32x4){0.f, 0.f, 0.f, 0.f};
        __builtin_amdgcn_s_setprio(1);
        #pragma unroll
        for (int kk = 0; kk < 4; ++kk) {
            #pragma unroll
            for (int c = 0; c < 4; ++c) {
                int rk = c * 16 + lr;
                bf16x8 kf = ldbf8(&ktc[rk * 128 + (((kk * 4 + lg) ^ (rk & 7)) << 3)]);
                s[c] = MFMA16(qf[kk], kf, s[c]);
            }
        }
        __builtin_amdgcn_s_setprio(0);
        // ---- online softmax ----
        float sc[4];
        #pragma unroll
        for (int i = 0; i < 4; ++i) {
            float v = fmaxf(fmaxf(s[0][i], s[1][i]), fmaxf(s[2][i], s[3][i]));
            v = fmaxf(v, __shfl_xor(v, 1));
            v = fmaxf(v, __shfl_xor(v, 2));
            v = fmaxf(v, __shfl_xor(v, 4));
            v = fmaxf(v, __shfl_xor(v, 8));
            float mnew = fmaxf(m_i[i], v);
            sc[i] = __expf(m_i[i] - mnew);
            float sum = 0.f;
            #pragma unroll
            for (int c = 0; c < 4; ++c) {
                float p = __expf(s[c][i] - mnew);
                s[c][i] = p;
                sum += p;
            }
            sum += __shfl_xor(sum, 1);
            sum += __shfl_xor(sum, 2);
            sum += __shfl_xor(sum, 4);
            sum += __shfl_xor(sum, 8);
            l_i[i] = l_i[i] * sc[i] + sum;
            m_i[i] = mnew;
        }
        #pragma unroll
        for (int d0 = 0; d0 < 8; ++d0)
            #pragma unroll
            for (int i = 0; i < 4; ++i) o[d0][i] *= sc[i];
        // ---- issue K[t+1] stage ----
        {
            const unsigned short* knext =
                fpb + (size_t)(kvbase + (((t + 1) & (NTILES - 1)) << 6)) * NCP;
            gld16(knext + offK[0], ktw0[cur ^ 1]);
            gld16(knext + offK[1], ktw0[cur ^ 1] + 64 * 8);
        }
        SCHED0();
        asm volatile("s_waitcnt vmcnt(2)" ::: "memory");  // V landed, K in flight
        BAR();
        // ---- P -> LDS -> A-fragment ----
        #pragma unroll
        for (int c = 0; c < 4; ++c)
            #pragma unroll
            for (int i = 0; i < 4; ++i)
                p_lds[lg * 4 + i][c * 16 + lr] = f2bf(s[c][i]);
        asm volatile("s_waitcnt lgkmcnt(0)" ::: "memory");
        SCHED0();
        bf16x8 pa[2];
        #pragma unroll
        for (int kk2 = 0; kk2 < 2; ++kk2)
            pa[kk2] = ldbf8(&p_lds[lr][kk2 * 32 + lg * 8]);
        // ---- O += P V ----
        __builtin_amdgcn_s_setprio(1);
        #pragma unroll
        for (int kk2 = 0; kk2 < 2; ++kk2) {
            #pragma unroll
            for (int d0 = 0; d0 < 8; ++d0) {
                int rv = d0 * 16 + lr;
                bf16x8 vf = ldbf8(&vt[rv * 64 + (((kk2 * 4 + lg) ^ (rv & 7)) << 3)]);
                o[d0] = MFMA16(pa[kk2], vf, o[d0]);
            }
        }
        __builtin_amdgcn_s_setprio(0);
        SCHED0();
        asm volatile("s_waitcnt vmcnt(0)" ::: "memory");  // K[t+1] landed
        BAR();
        vsrc += 64;
    }
    // write unnormalized partials
    const size_t pbase = (size_t)(b * SPLIT + sidx) * NN + q0;
    #pragma unroll
    for (int d0 = 0; d0 < 8; ++d0)
        #pragma unroll
        for (int i = 0; i < 4; ++i)
            po[(pbase + lg * 4 + i) * NCP + d0 * 16 + lr] = o[d0][i];
    if (lr == 0) {
        #pragma unroll
        for (int i = 0; i < 4; ++i) {
            mbuf[pbase + lg * 4 + i] = m_i[i];
            lbuf[pbase + lg * 4 + i] = l_i[i];
        }
    }
}

// ---------------- merge partials -> pt (bf16) ----------------
__global__ __launch_bounds__(256) void merge_kernel(
    const float* __restrict__ po, const float* __restrict__ mbuf,
    const float* __restrict__ lbuf, unsigned short* __restrict__ pt)
{
    const int b = blockIdx.y;
    const int n = blockIdx.x * 4 + (threadIdx.x >> 6);
    const int lane = threadIdx.x & 63;
    float m_s[SPLIT], l_s[SPLIT];
    float M = -INFINITY;
    #pragma unroll
    for (int s = 0; s < SPLIT; ++s) {
        m_s[s] = mbuf[(size_t)(b * SPLIT + s) * NN + n];
        l_s[s] = lbuf[(size_t)(b * SPLIT + s) * NN + n];
        M = fmaxf(M, m_s[s]);
    }
    float L = 0.f, wgt[SPLIT];
    #pragma unroll
    for (int s = 0; s < SPLIT; ++s) { wgt[s] = __expf(m_s[s] - M); L += wgt[s] * l_s[s]; }
    const float inv = 1.f / L;
    float ax = 0.f, ay = 0.f;
    #pragma unroll
    for (int s = 0; s < SPLIT; ++s) {
        const float2* row = (const float2*)(po + ((size_t)(b * SPLIT + s) * NN + n) * NCP);
        float2 v = row[lane];
        ax += wgt[s] * v.x;
        ay += wgt[s] * v.y;
    }
    unsigned short* dst = pt + ((size_t)b * NN + n) * NCP + lane * 2;
    dst[0] = f2bf(ax * inv);
    dst[1] = f2bf(ay * inv);
}

// ---------------- aug via MFMA: out[b][k][n] = cam + sum_d ct[b][k][d]*pt[b][n][d] ----
// wave computes 16 n x 32 k (20 valid). A = pt rows, B = ct^T.
__global__ __launch_bounds__(256) void aug_kernel(
    const float* __restrict__ cam, const float* __restrict__ ct,
    const unsigned short* __restrict__ pt, float* __restrict__ out)
{
    const int b = blockIdx.y;
    const int tid = threadIdx.x, wid = tid >> 6, lane = tid & 63;
    const int lg = lane >> 4, lr = lane & 15;
    const int n0 = blockIdx.x * 64 + wid * 16;
    const unsigned short* ptb = pt + (size_t)b * NN * NCP;
    const float* ctb = ct + (size_t)b * NK * NCP;

    f32x4 acc[2];
    acc[0] = (f32x4){0.f, 0.f, 0.f, 0.f};
    acc[1] = (f32x4){0.f, 0.f, 0.f, 0.f};
    #pragma unroll
    for (int kk = 0; kk < 4; ++kk) {
        bf16x8 af = ldbf8(&ptb[(size_t)(n0 + lr) * NCP + kk * 32 + lg * 8]);
        #pragma unroll
        for (int c = 0; c < 2; ++c) {
            int k = c * 16 + lr;
            short8 bv;
            if (k < NK) {
                const float* cr = &ctb[(size_t)k * NCP + kk * 32 + lg * 8];
                #pragma unroll
                for (int j = 0; j < 8; ++j) bv[j] = (short)f2bf(cr[j]);
            } else {
                #pragma unroll
                for (int j = 0; j < 8; ++j) bv[j] = 0;
            }
            acc[c] = MFMA16(af, __builtin_bit_cast(bf16x8, bv), acc[c]);
        }
    }
    #pragma unroll
    for (int c = 0; c < 2; ++c) {
        int k = c * 16 + lr;
        if (k < NK) {
            #pragma unroll
            for (int i = 0; i < 4; ++i) {
                size_t off = ((size_t)b * NK + k) * NN + n0 + lg * 4 + i;
                out[off] = cam[off] + acc[c][i];
            }
        }
    }
}

extern "C" void kernel_launch(void* const* d_in, const int* in_sizes, int n_in,
                              void* d_out, int out_size, void* d_ws, size_t ws_size,
                              hipStream_t stream) {
    const float* feat = (const float*)d_in[0];
    const float* cam  = (const float*)d_in[1];
    const float* wpr  = (const float*)d_in[2];
    const float* bpr  = (const float*)d_in[3];
    float* out = (float*)d_out;

    const size_t MB = 1024 * 1024;
    char* ws = (char*)d_ws;
    unsigned short* fp  = (unsigned short*)(ws);             // 4 MB
    unsigned short* fpT = (unsigned short*)(ws + 4 * MB);    // 4 MB
    unsigned short* pt  = (unsigned short*)(ws + 8 * MB);    // 4 MB
    float* ct           = (float*)(ws + 12 * MB);            // 40 KB
    float* po           = (float*)(ws + 13 * MB);            // 32 MB fp32 partial O
    float* mbuf         = (float*)(ws + 45 * MB);            // 256 KB
    float* lbuf         = (float*)(ws + 46 * MB);            // 256 KB

    hipMemsetAsync(ct, 0, (size_t)NB * NK * NCP * sizeof(float), stream);
    proj_kernel<<<dim3(NN / 64, NB), 256, 0, stream>>>(feat, wpr, bpr, fp, fpT);
    ct_kernel<<<NB * NK * 16, 128, 0, stream>>>(cam, fp, ct);
    attn_partial_kernel<<<dim3(NN / 128, SPLIT, NB), 512, 0, stream>>>(fp, fpT, po, mbuf, lbuf);
    merge_kernel<<<dim3(NN / 4, NB), 256, 0, stream>>>(po, mbuf, lbuf, pt);
    aug_kernel<<<dim3(NN / 64, NB), 256, 0, stream>>>(cam, ct, pt, out);
}

// Round 4
// 107.847 us; speedup vs baseline: 4.0933x; 1.1758x over previous
//
#include <hip/hip_runtime.h>
#include <hip/hip_bf16.h>
#include <math.h>

#define NB 4
#define NC 512
#define NN 4096
#define NK 20
#define NCP 128
#define SPLIT 4
#define CHUNK (NN / SPLIT)   // 1024 keys per split
#define NTILES (CHUNK / 64)  // 16

typedef __bf16 bf16x8 __attribute__((ext_vector_type(8)));
typedef float f32x4 __attribute__((ext_vector_type(4)));
typedef short short8 __attribute__((ext_vector_type(8)));
typedef unsigned int uint4v __attribute__((ext_vector_type(4)));

static __device__ __forceinline__ unsigned short f2bf(float f) {
    unsigned int u = __builtin_bit_cast(unsigned int, f);
    unsigned int r = (u + 0x7FFFu + ((u >> 16) & 1u)) >> 16;
    return (unsigned short)r;
}
static __device__ __forceinline__ float bf2f(unsigned short h) {
    unsigned int u = ((unsigned int)h) << 16;
    return __builtin_bit_cast(float, u);
}
static __device__ __forceinline__ bf16x8 ldbf8(const unsigned short* p) {
    return __builtin_bit_cast(bf16x8, *reinterpret_cast<const short8*>(p));
}
static __device__ __forceinline__ void gld16(const unsigned short* g, unsigned short* l) {
    __builtin_amdgcn_global_load_lds(
        (const __attribute__((address_space(1))) unsigned int*)g,
        (__attribute__((address_space(3))) unsigned int*)l, 16, 0, 0);
}
static __device__ __forceinline__ unsigned int cvtpk(float lo, float hi) {
    unsigned int r;
    asm("v_cvt_pk_bf16_f32 %0, %1, %2" : "=v"(r) : "v"(lo), "v"(hi));
    return r;
}

#define MFMA16(a, b, c) __builtin_amdgcn_mfma_f32_16x16x32_bf16(a, b, c, 0, 0, 0)
#define SCHED0() __builtin_amdgcn_sched_barrier(0)
#define BAR() do { SCHED0(); __builtin_amdgcn_s_barrier(); SCHED0(); } while (0)

// ---------------- proj: fp[b][n][d] = sum_c feat[b][c][n]*w[d][c] + bias[d] ----
__global__ __launch_bounds__(256) void proj_kernel(
    const float* __restrict__ feat, const float* __restrict__ w,
    const float* __restrict__ bias, unsigned short* __restrict__ fp,
    unsigned short* __restrict__ fpT)
{
    const int b = blockIdx.y;
    const int n0 = blockIdx.x * 64;
    const int tid = threadIdx.x;
    const int wid = tid >> 6;
    const int lane = tid & 63;
    const int lg = lane >> 4, lr = lane & 15;

    __shared__ unsigned short lds_f[64][40];   // [n][c] bf16, +8 pad

    const float* featb = feat + (size_t)b * NC * NN;

    f32x4 acc[2][4];
    #pragma unroll
    for (int i = 0; i < 2; ++i)
        #pragma unroll
        for (int j = 0; j < 4; ++j) acc[i][j] = (f32x4){0.f, 0.f, 0.f, 0.f};

    for (int c0 = 0; c0 < NC; c0 += 32) {
        __syncthreads();
        #pragma unroll
        for (int it = 0; it < 2; ++it) {
            int idx = it * 256 + tid;          // 0..511
            int cc = idx >> 4, q = idx & 15;
            float4 v = *reinterpret_cast<const float4*>(
                &featb[(size_t)(c0 + cc) * NN + n0 + q * 4]);
            lds_f[q * 4 + 0][cc] = f2bf(v.x);
            lds_f[q * 4 + 1][cc] = f2bf(v.y);
            lds_f[q * 4 + 2][cc] = f2bf(v.z);
            lds_f[q * 4 + 3][cc] = f2bf(v.w);
        }
        __syncthreads();
        bf16x8 afr[2];
        #pragma unroll
        for (int dt = 0; dt < 2; ++dt) {
            const float4* wr = reinterpret_cast<const float4*>(
                w + (size_t)(wid * 32 + dt * 16 + lr) * NC + c0 + lg * 8);
            float4 w0 = wr[0], w1 = wr[1];
            short8 a;
            a[0] = (short)f2bf(w0.x); a[1] = (short)f2bf(w0.y);
            a[2] = (short)f2bf(w0.z); a[3] = (short)f2bf(w0.w);
            a[4] = (short)f2bf(w1.x); a[5] = (short)f2bf(w1.y);
            a[6] = (short)f2bf(w1.z); a[7] = (short)f2bf(w1.w);
            afr[dt] = __builtin_bit_cast(bf16x8, a);
        }
        #pragma unroll
        for (int n1 = 0; n1 < 4; ++n1) {
            bf16x8 bfr = ldbf8(&lds_f[n1 * 16 + lr][lg * 8]);
            #pragma unroll
            for (int dt = 0; dt < 2; ++dt)
                acc[dt][n1] = MFMA16(afr[dt], bfr, acc[dt][n1]);
        }
    }
    #pragma unroll
    for (int dt = 0; dt < 2; ++dt)
        #pragma unroll
        for (int n1 = 0; n1 < 4; ++n1)
            #pragma unroll
            for (int i = 0; i < 4; ++i) {
                int d = wid * 32 + dt * 16 + lg * 4 + i;
                int n = n0 + n1 * 16 + lr;
                unsigned short h = f2bf(acc[dt][n1][i] + bias[d]);
                fp[((size_t)b * NN + n) * NCP + d] = h;
                fpT[((size_t)b * NCP + d) * NN + n] = h;
            }
}

// ---------------- class_term: ct[b][k][d] = sum_n cam[b][k][n]*fp[b][n][d] ----
__global__ __launch_bounds__(128) void ct_kernel(
    const float* __restrict__ cam, const unsigned short* __restrict__ fp,
    float* __restrict__ ct)
{
    const int bid = blockIdx.x;
    const int chunk = bid & 15;         // 16 chunks of 256 n
    const int bk = bid >> 4;
    const int b = bk / NK, k = bk % NK;
    const int d = threadIdx.x;
    const float* camp = cam + ((size_t)b * NK + k) * NN + chunk * 256;
    const unsigned short* fpp = fp + ((size_t)b * NN + chunk * 256) * NCP + d;
    float acc = 0.f;
    #pragma unroll 8
    for (int n = 0; n < 256; ++n)
        acc += camp[n] * bf2f(fpp[(size_t)n * NCP]);
    atomicAdd(&ct[((size_t)b * NK + k) * NCP + d], acc);
}

// ---------------- attention partials over a 1024-key chunk ----------------
// 512 threads = 8 waves; wave owns 16 q-rows. Swapped QK^T: S^T = K·Q^T so
// each lane owns q = lane&15 (softmax mostly lane-local). PV: O^T = V^T·P^T.
__global__ __launch_bounds__(512, 4) void attn_partial_kernel(
    const unsigned short* __restrict__ fp, const unsigned short* __restrict__ fpT,
    float* __restrict__ po, float* __restrict__ mbuf, float* __restrict__ lbuf)
{
    const int b = blockIdx.z;
    const int sidx = blockIdx.y;
    const int tid = threadIdx.x;
    const int wid = tid >> 6;
    const int lane = tid & 63;
    const int lg = lane >> 4, lr = lane & 15;
    const int q0 = blockIdx.x * 128 + wid * 16;
    const int kvbase = sidx * CHUNK;

    __shared__ unsigned short kt[2][64 * 128];       // K dbuf, 16B-chunk swizzled
    __shared__ unsigned short vt[128 * 64];          // V single buf, swizzled
    __shared__ __attribute__((aligned(16))) unsigned int p_all[8][16][32]; // [q][k2] u32, swizzled
    unsigned int (*p_lds)[32] = p_all[wid];

    const unsigned short* fpb  = fp  + (size_t)b * NN * NCP;
    const unsigned short* fpTb = fpT + (size_t)b * NCP * NN;

    // per-lane swizzled staging offsets
    int offK[2], offV[2];
    #pragma unroll
    for (int i = 0; i < 2; ++i) {
        int slot = wid * 128 + i * 64 + lane;
        int rk = slot >> 4, ck = slot & 15;
        offK[i] = rk * NCP + ((ck ^ (rk & 7)) << 3);
        int rv = slot >> 3, cv = slot & 7;
        offV[i] = rv * NN + ((cv ^ (rv & 7)) << 3);
    }
    unsigned short* ktw0[2] = { &kt[0][(wid * 128) * 8], &kt[1][(wid * 128) * 8] };
    unsigned short* vtw0 = &vt[(wid * 128) * 8];

    // Q fragments (B operand of swapped QK^T): col=q=lr, inner d = kk*32+lg*8+j
    bf16x8 qf[4];
    #pragma unroll
    for (int kk = 0; kk < 4; ++kk)
        qf[kk] = ldbf8(&fpb[(size_t)(q0 + lr) * NCP + kk * 32 + lg * 8]);

    f32x4 o[8];   // O^T: o[d0][i] = O^T[d0*16+lg*4+i][q=lr] (unnormalized)
    #pragma unroll
    for (int i = 0; i < 8; ++i) o[i] = (f32x4){0.f, 0.f, 0.f, 0.f};
    float m_i = -INFINITY, l_i = 0.f;

    // prologue: stage K[0]
    {
        const unsigned short* k0 = fpb + (size_t)kvbase * NCP;
        gld16(k0 + offK[0], ktw0[0]);
        gld16(k0 + offK[1], ktw0[0] + 64 * 8);
    }
    SCHED0();
    asm volatile("s_waitcnt vmcnt(0)" ::: "memory");
    BAR();

    const unsigned short* vsrc = fpTb + kvbase;

    for (int t = 0; t < NTILES; ++t) {
        const int cur = t & 1;
        // ---- issue V[t] stage ----
        gld16(vsrc + offV[0], vtw0);
        gld16(vsrc + offV[1], vtw0 + 64 * 8);
        SCHED0();
        // ---- S^T = K Q^T from kt[cur] ----
        const unsigned short* ktc = &kt[cur][0];
        f32x4 s[4];
        #pragma unroll
        for (int c = 0; c < 4; ++c) s[c] = (f32x4){0.f, 0.f, 0.f, 0.f};
        __builtin_amdgcn_s_setprio(1);
        #pragma unroll
        for (int kk = 0; kk < 4; ++kk) {
            #pragma unroll
            for (int c = 0; c < 4; ++c) {
                int rk = c * 16 + lr;
                bf16x8 kf = ldbf8(&ktc[rk * 128 + (((kk * 4 + lg) ^ (rk & 7)) << 3)]);
                s[c] = MFMA16(kf, qf[kk], s[c]);   // swapped operands
            }
        }
        __builtin_amdgcn_s_setprio(0);
        // ---- issue K[t+1] stage (overlaps softmax) ----
        {
            const unsigned short* knext =
                fpb + (size_t)(kvbase + (((t + 1) & (NTILES - 1)) << 6)) * NCP;
            gld16(knext + offK[0], ktw0[cur ^ 1]);
            gld16(knext + offK[1], ktw0[cur ^ 1] + 64 * 8);
        }
        SCHED0();
        // ---- online softmax: lane owns q=lr; s[c][i] = S[k=c*16+lg*4+i][q] ----
        float pmax = s[0][0];
        #pragma unroll
        for (int c = 0; c < 4; ++c)
            #pragma unroll
            for (int i = 0; i < 4; ++i) pmax = fmaxf(pmax, s[c][i]);
        pmax = fmaxf(pmax, __shfl_xor(pmax, 16));
        pmax = fmaxf(pmax, __shfl_xor(pmax, 32));
        if (!__all(pmax - m_i <= 8.f)) {   // defer-max (THR=8)
            float mnew = fmaxf(m_i, pmax);
            float sc = __expf(m_i - mnew);
            l_i *= sc;
            #pragma unroll
            for (int d0 = 0; d0 < 8; ++d0)
                #pragma unroll
                for (int i = 0; i < 4; ++i) o[d0][i] *= sc;
            m_i = mnew;
        }
        float sum = 0.f;
        #pragma unroll
        for (int c = 0; c < 4; ++c)
            #pragma unroll
            for (int i = 0; i < 4; ++i) {
                float e = __expf(s[c][i] - m_i);
                s[c][i] = e;
                sum += e;
            }
        sum += __shfl_xor(sum, 16);
        sum += __shfl_xor(sum, 32);
        l_i += sum;
        // ---- P^T -> bf16 pairs -> swizzled LDS (wave-private, no barrier) ----
        #pragma unroll
        for (int c = 0; c < 4; ++c) {
            unsigned int w0 = cvtpk(s[c][0], s[c][1]);
            unsigned int w1 = cvtpk(s[c][2], s[c][3]);
            int col = (c * 8 + lg * 2) ^ ((lr & 3) << 2);
            p_lds[lr][col]     = w0;
            p_lds[lr][col + 1] = w1;
        }
        asm volatile("s_waitcnt vmcnt(2)" ::: "memory");  // V landed, K in flight
        BAR();
        // ---- read P^T B-fragments ----
        bf16x8 paf[2];
        #pragma unroll
        for (int kk2 = 0; kk2 < 2; ++kk2) {
            int col = (kk2 * 16 + lg * 4) ^ ((lr & 3) << 2);
            uint4v u = *reinterpret_cast<const uint4v*>(&p_lds[lr][col]);
            paf[kk2] = __builtin_bit_cast(bf16x8, u);
        }
        // ---- O^T += V^T P^T ----
        __builtin_amdgcn_s_setprio(1);
        #pragma unroll
        for (int kk2 = 0; kk2 < 2; ++kk2) {
            #pragma unroll
            for (int d0 = 0; d0 < 8; ++d0) {
                int rv = d0 * 16 + lr;
                bf16x8 vf = ldbf8(&vt[rv * 64 + (((kk2 * 4 + lg) ^ (rv & 7)) << 3)]);
                o[d0] = MFMA16(vf, paf[kk2], o[d0]);
            }
        }
        __builtin_amdgcn_s_setprio(0);
        SCHED0();
        asm volatile("s_waitcnt vmcnt(0)" ::: "memory");  // K[t+1] landed
        BAR();
        vsrc += 64;
    }
    // write unnormalized partials: po[n=q0+lr][d], d = d0*16+lg*4+i consecutive
    const size_t pbase = (size_t)(b * SPLIT + sidx) * NN + q0;
    #pragma unroll
    for (int d0 = 0; d0 < 8; ++d0)
        *reinterpret_cast<f32x4*>(&po[(pbase + lr) * NCP + d0 * 16 + lg * 4]) = o[d0];
    if (lane < 16) {
        mbuf[pbase + lr] = m_i;
        lbuf[pbase + lr] = l_i;
    }
}

// ---------------- merge partials -> pt (bf16) ----------------
__global__ __launch_bounds__(256) void merge_kernel(
    const float* __restrict__ po, const float* __restrict__ mbuf,
    const float* __restrict__ lbuf, unsigned short* __restrict__ pt)
{
    const int b = blockIdx.y;
    const int n = blockIdx.x * 4 + (threadIdx.x >> 6);
    const int lane = threadIdx.x & 63;
    float m_s[SPLIT], l_s[SPLIT];
    float M = -INFINITY;
    #pragma unroll
    for (int s = 0; s < SPLIT; ++s) {
        m_s[s] = mbuf[(size_t)(b * SPLIT + s) * NN + n];
        l_s[s] = lbuf[(size_t)(b * SPLIT + s) * NN + n];
        M = fmaxf(M, m_s[s]);
    }
    float L = 0.f, wgt[SPLIT];
    #pragma unroll
    for (int s = 0; s < SPLIT; ++s) { wgt[s] = __expf(m_s[s] - M); L += wgt[s] * l_s[s]; }
    const float inv = 1.f / L;
    float ax = 0.f, ay = 0.f;
    #pragma unroll
    for (int s = 0; s < SPLIT; ++s) {
        const float2* row = (const float2*)(po + ((size_t)(b * SPLIT + s) * NN + n) * NCP);
        float2 v = row[lane];
        ax += wgt[s] * v.x;
        ay += wgt[s] * v.y;
    }
    unsigned short* dst = pt + ((size_t)b * NN + n) * NCP + lane * 2;
    dst[0] = f2bf(ax * inv);
    dst[1] = f2bf(ay * inv);
}

// ---------------- aug via MFMA: out[b][k][n] = cam + sum_d ct[b][k][d]*pt[b][n][d] ----
__global__ __launch_bounds__(256) void aug_kernel(
    const float* __restrict__ cam, const float* __restrict__ ct,
    const unsigned short* __restrict__ pt, float* __restrict__ out)
{
    const int b = blockIdx.y;
    const int tid = threadIdx.x, wid = tid >> 6, lane = tid & 63;
    const int lg = lane >> 4, lr = lane & 15;
    const int n0 = blockIdx.x * 64 + wid * 16;
    const unsigned short* ptb = pt + (size_t)b * NN * NCP;
    const float* ctb = ct + (size_t)b * NK * NCP;

    f32x4 acc[2];
    acc[0] = (f32x4){0.f, 0.f, 0.f, 0.f};
    acc[1] = (f32x4){0.f, 0.f, 0.f, 0.f};
    #pragma unroll
    for (int kk = 0; kk < 4; ++kk) {
        bf16x8 af = ldbf8(&ptb[(size_t)(n0 + lr) * NCP + kk * 32 + lg * 8]);
        #pragma unroll
        for (int c = 0; c < 2; ++c) {
            int k = c * 16 + lr;
            short8 bv;
            if (k < NK) {
                const float* cr = &ctb[(size_t)k * NCP + kk * 32 + lg * 8];
                #pragma unroll
                for (int j = 0; j < 8; ++j) bv[j] = (short)f2bf(cr[j]);
            } else {
                #pragma unroll
                for (int j = 0; j < 8; ++j) bv[j] = 0;
            }
            acc[c] = MFMA16(af, __builtin_bit_cast(bf16x8, bv), acc[c]);
        }
    }
    #pragma unroll
    for (int c = 0; c < 2; ++c) {
        int k = c * 16 + lr;
        if (k < NK) {
            #pragma unroll
            for (int i = 0; i < 4; ++i) {
                size_t off = ((size_t)b * NK + k) * NN + n0 + lg * 4 + i;
                out[off] = cam[off] + acc[c][i];
            }
        }
    }
}

extern "C" void kernel_launch(void* const* d_in, const int* in_sizes, int n_in,
                              void* d_out, int out_size, void* d_ws, size_t ws_size,
                              hipStream_t stream) {
    const float* feat = (const float*)d_in[0];
    const float* cam  = (const float*)d_in[1];
    const float* wpr  = (const float*)d_in[2];
    const float* bpr  = (const float*)d_in[3];
    float* out = (float*)d_out;

    const size_t MB = 1024 * 1024;
    char* ws = (char*)d_ws;
    unsigned short* fp  = (unsigned short*)(ws);             // 4 MB
    unsigned short* fpT = (unsigned short*)(ws + 4 * MB);    // 4 MB
    unsigned short* pt  = (unsigned short*)(ws + 8 * MB);    // 4 MB
    float* ct           = (float*)(ws + 12 * MB);            // 40 KB
    float* po           = (float*)(ws + 13 * MB);            // 32 MB fp32 partial O
    float* mbuf         = (float*)(ws + 45 * MB);            // 256 KB
    float* lbuf         = (float*)(ws + 46 * MB);            // 256 KB

    hipMemsetAsync(ct, 0, (size_t)NB * NK * NCP * sizeof(float), stream);
    proj_kernel<<<dim3(NN / 64, NB), 256, 0, stream>>>(feat, wpr, bpr, fp, fpT);
    ct_kernel<<<NB * NK * 16, 128, 0, stream>>>(cam, fp, ct);
    attn_partial_kernel<<<dim3(NN / 128, SPLIT, NB), 512, 0, stream>>>(fp, fpT, po, mbuf, lbuf);
    merge_kernel<<<dim3(NN / 4, NB), 256, 0, stream>>>(po, mbuf, lbuf, pt);
    aug_kernel<<<dim3(NN / 64, NB), 256, 0, stream>>>(cam, ct, pt, out);
}

// Round 5
// 105.525 us; speedup vs baseline: 4.1834x; 1.0220x over previous
//
#include <hip/hip_runtime.h>
#include <hip/hip_bf16.h>
#include <math.h>

#define NB 4
#define NC 512
#define NN 4096
#define NK 20
#define NCP 128
#define SPLIT 4
#define CHUNK (NN / SPLIT)   // 1024 keys per split
#define NTILES (CHUNK / 64)  // 16

typedef __bf16 bf16x8 __attribute__((ext_vector_type(8)));
typedef float f32x4 __attribute__((ext_vector_type(4)));
typedef short short8 __attribute__((ext_vector_type(8)));
typedef unsigned int uint4v __attribute__((ext_vector_type(4)));

static __device__ __forceinline__ unsigned short f2bf(float f) {
    unsigned int u = __builtin_bit_cast(unsigned int, f);
    unsigned int r = (u + 0x7FFFu + ((u >> 16) & 1u)) >> 16;
    return (unsigned short)r;
}
static __device__ __forceinline__ float bf2f(unsigned short h) {
    unsigned int u = ((unsigned int)h) << 16;
    return __builtin_bit_cast(float, u);
}
static __device__ __forceinline__ bf16x8 ldbf8(const unsigned short* p) {
    return __builtin_bit_cast(bf16x8, *reinterpret_cast<const short8*>(p));
}
static __device__ __forceinline__ void gld16(const unsigned short* g, unsigned short* l) {
    __builtin_amdgcn_global_load_lds(
        (const __attribute__((address_space(1))) unsigned int*)g,
        (__attribute__((address_space(3))) unsigned int*)l, 16, 0, 0);
}
static __device__ __forceinline__ unsigned int cvtpk(float lo, float hi) {
    unsigned int r;
    asm("v_cvt_pk_bf16_f32 %0, %1, %2" : "=v"(r) : "v"(lo), "v"(hi));
    return r;
}

#define MFMA16(a, b, c) __builtin_amdgcn_mfma_f32_16x16x32_bf16(a, b, c, 0, 0, 0)
#define SCHED0() __builtin_amdgcn_sched_barrier(0)
#define BAR() do { SCHED0(); __builtin_amdgcn_s_barrier(); SCHED0(); } while (0)

// ---------------- proj: fp[b][n][d] = sum_c feat[b][c][n]*w[d][c] + bias[d] ----
__global__ __launch_bounds__(256) void proj_kernel(
    const float* __restrict__ feat, const float* __restrict__ w,
    const float* __restrict__ bias, unsigned short* __restrict__ fp,
    unsigned short* __restrict__ fpT)
{
    const int b = blockIdx.y;
    const int n0 = blockIdx.x * 64;
    const int tid = threadIdx.x;
    const int wid = tid >> 6;
    const int lane = tid & 63;
    const int lg = lane >> 4, lr = lane & 15;

    __shared__ unsigned short lds_f[64][40];   // [n][c] bf16, +8 pad

    const float* featb = feat + (size_t)b * NC * NN;

    f32x4 acc[2][4];
    #pragma unroll
    for (int i = 0; i < 2; ++i)
        #pragma unroll
        for (int j = 0; j < 4; ++j) acc[i][j] = (f32x4){0.f, 0.f, 0.f, 0.f};

    for (int c0 = 0; c0 < NC; c0 += 32) {
        __syncthreads();
        #pragma unroll
        for (int it = 0; it < 2; ++it) {
            int idx = it * 256 + tid;          // 0..511
            int cc = idx >> 4, q = idx & 15;
            float4 v = *reinterpret_cast<const float4*>(
                &featb[(size_t)(c0 + cc) * NN + n0 + q * 4]);
            lds_f[q * 4 + 0][cc] = f2bf(v.x);
            lds_f[q * 4 + 1][cc] = f2bf(v.y);
            lds_f[q * 4 + 2][cc] = f2bf(v.z);
            lds_f[q * 4 + 3][cc] = f2bf(v.w);
        }
        __syncthreads();
        bf16x8 afr[2];
        #pragma unroll
        for (int dt = 0; dt < 2; ++dt) {
            const float4* wr = reinterpret_cast<const float4*>(
                w + (size_t)(wid * 32 + dt * 16 + lr) * NC + c0 + lg * 8);
            float4 w0 = wr[0], w1 = wr[1];
            short8 a;
            a[0] = (short)f2bf(w0.x); a[1] = (short)f2bf(w0.y);
            a[2] = (short)f2bf(w0.z); a[3] = (short)f2bf(w0.w);
            a[4] = (short)f2bf(w1.x); a[5] = (short)f2bf(w1.y);
            a[6] = (short)f2bf(w1.z); a[7] = (short)f2bf(w1.w);
            afr[dt] = __builtin_bit_cast(bf16x8, a);
        }
        #pragma unroll
        for (int n1 = 0; n1 < 4; ++n1) {
            bf16x8 bfr = ldbf8(&lds_f[n1 * 16 + lr][lg * 8]);
            #pragma unroll
            for (int dt = 0; dt < 2; ++dt)
                acc[dt][n1] = MFMA16(afr[dt], bfr, acc[dt][n1]);
        }
    }
    #pragma unroll
    for (int dt = 0; dt < 2; ++dt)
        #pragma unroll
        for (int n1 = 0; n1 < 4; ++n1)
            #pragma unroll
            for (int i = 0; i < 4; ++i) {
                int d = wid * 32 + dt * 16 + lg * 4 + i;
                int n = n0 + n1 * 16 + lr;
                unsigned short h = f2bf(acc[dt][n1][i] + bias[d]);
                fp[((size_t)b * NN + n) * NCP + d] = h;
                fpT[((size_t)b * NCP + d) * NN + n] = h;
            }
}

// ---------------- class_term: ct[b][k][d] = sum_n cam[b][k][n]*fp[b][n][d] ----
__global__ __launch_bounds__(128) void ct_kernel(
    const float* __restrict__ cam, const unsigned short* __restrict__ fp,
    float* __restrict__ ct)
{
    const int bid = blockIdx.x;
    const int chunk = bid & 15;         // 16 chunks of 256 n
    const int bk = bid >> 4;
    const int b = bk / NK, k = bk % NK;
    const int d = threadIdx.x;
    const float* camp = cam + ((size_t)b * NK + k) * NN + chunk * 256;
    const unsigned short* fpp = fp + ((size_t)b * NN + chunk * 256) * NCP + d;
    float acc = 0.f;
    #pragma unroll 8
    for (int n = 0; n < 256; ++n)
        acc += camp[n] * bf2f(fpp[(size_t)n * NCP]);
    atomicAdd(&ct[((size_t)b * NK + k) * NCP + d], acc);
}

// ---------------- attention partials over a 1024-key chunk ----------------
// 512 threads = 8 waves; wave owns 16 q-rows. Swapped QK^T (S^T = K·Q^T),
// P exchange entirely in registers via permlane32/16_swap, K+V double-buffered,
// ONE barrier per tile with full-tile compute covering the staging latency.
__global__ __launch_bounds__(512, 4) void attn_partial_kernel(
    const unsigned short* __restrict__ fp, const unsigned short* __restrict__ fpT,
    float* __restrict__ po, float* __restrict__ mbuf, float* __restrict__ lbuf)
{
    const int b = blockIdx.z;
    const int sidx = blockIdx.y;
    const int tid = threadIdx.x;
    const int wid = tid >> 6;
    const int lane = tid & 63;
    const int lg = lane >> 4, lr = lane & 15;
    const int q0 = blockIdx.x * 128 + wid * 16;
    const int kvbase = sidx * CHUNK;

    __shared__ unsigned short kt[2][64 * 128];   // K dbuf, 16B-chunk swizzled
    __shared__ unsigned short vt[2][128 * 64];   // V dbuf, swizzled

    const unsigned short* fpb  = fp  + (size_t)b * NN * NCP;
    const unsigned short* fpTb = fpT + (size_t)b * NCP * NN;

    // per-lane swizzled staging offsets
    int offK[2], offV[2];
    #pragma unroll
    for (int i = 0; i < 2; ++i) {
        int slot = wid * 128 + i * 64 + lane;
        int rk = slot >> 4, ck = slot & 15;
        offK[i] = rk * NCP + ((ck ^ (rk & 7)) << 3);
        int rv = slot >> 3, cv = slot & 7;
        offV[i] = rv * NN + ((cv ^ (rv & 7)) << 3);
    }
    unsigned short* ktw0[2] = { &kt[0][wid * 1024], &kt[1][wid * 1024] };
    unsigned short* vtw0[2] = { &vt[0][wid * 1024], &vt[1][wid * 1024] };

    // Q fragments (B operand of swapped QK^T): col=q=lr, inner d = kk*32+lg*8+j
    bf16x8 qf[4];
    #pragma unroll
    for (int kk = 0; kk < 4; ++kk)
        qf[kk] = ldbf8(&fpb[(size_t)(q0 + lr) * NCP + kk * 32 + lg * 8]);

    f32x4 o[8];   // O^T: o[d0][i] = O^T[d0*16+lg*4+i][q=lr] (unnormalized)
    #pragma unroll
    for (int i = 0; i < 8; ++i) o[i] = (f32x4){0.f, 0.f, 0.f, 0.f};
    float m_i = -INFINITY, l_i = 0.f;

    // prologue: stage K[0], V[0]
    {
        const unsigned short* k0 = fpb + (size_t)kvbase * NCP;
        const unsigned short* v0 = fpTb + kvbase;
        gld16(k0 + offK[0], ktw0[0]);
        gld16(k0 + offK[1], ktw0[0] + 512);
        gld16(v0 + offV[0], vtw0[0]);
        gld16(v0 + offV[1], vtw0[0] + 512);
    }
    SCHED0();
    asm volatile("s_waitcnt vmcnt(0)" ::: "memory");
    BAR();

    for (int t = 0; t < NTILES; ++t) {
        const int cur = t & 1;
        // ---- issue next-tile K/V stages into the other buffers ----
        {
            const int tn = (t + 1) & (NTILES - 1);
            const unsigned short* knext = fpb + (size_t)(kvbase + tn * 64) * NCP;
            const unsigned short* vnext = fpTb + kvbase + tn * 64;
            gld16(knext + offK[0], ktw0[cur ^ 1]);
            gld16(knext + offK[1], ktw0[cur ^ 1] + 512);
            gld16(vnext + offV[0], vtw0[cur ^ 1]);
            gld16(vnext + offV[1], vtw0[cur ^ 1] + 512);
        }
        SCHED0();
        // ---- S^T = K Q^T from kt[cur] ----
        const unsigned short* ktc = &kt[cur][0];
        f32x4 s[4];
        #pragma unroll
        for (int c = 0; c < 4; ++c) s[c] = (f32x4){0.f, 0.f, 0.f, 0.f};
        __builtin_amdgcn_s_setprio(1);
        #pragma unroll
        for (int kk = 0; kk < 4; ++kk) {
            #pragma unroll
            for (int c = 0; c < 4; ++c) {
                int rk = c * 16 + lr;
                bf16x8 kf = ldbf8(&ktc[rk * 128 + (((kk * 4 + lg) ^ (rk & 7)) << 3)]);
                s[c] = MFMA16(kf, qf[kk], s[c]);   // swapped operands
            }
        }
        __builtin_amdgcn_s_setprio(0);
        // ---- online softmax: lane owns q=lr; s[c][i] = S[k=c*16+lg*4+i][q] ----
        float pmax = s[0][0];
        #pragma unroll
        for (int c = 0; c < 4; ++c)
            #pragma unroll
            for (int i = 0; i < 4; ++i) pmax = fmaxf(pmax, s[c][i]);
        pmax = fmaxf(pmax, __shfl_xor(pmax, 16));
        pmax = fmaxf(pmax, __shfl_xor(pmax, 32));
        if (!__all(pmax - m_i <= 8.f)) {   // defer-max (THR=8)
            float mnew = fmaxf(m_i, pmax);
            float sc = __expf(m_i - mnew);
            l_i *= sc;
            #pragma unroll
            for (int d0 = 0; d0 < 8; ++d0)
                #pragma unroll
                for (int i = 0; i < 4; ++i) o[d0][i] *= sc;
            m_i = mnew;
        }
        float sum = 0.f;
        #pragma unroll
        for (int c = 0; c < 4; ++c)
            #pragma unroll
            for (int i = 0; i < 4; ++i) {
                float e = __expf(s[c][i] - m_i);
                s[c][i] = e;
                sum += e;
            }
        sum += __shfl_xor(sum, 16);
        sum += __shfl_xor(sum, 32);
        l_i += sum;
        // ---- P^T exchange fully in registers: cvt_pk + permlane swaps ----
        // holder word w[c][b] = bf16 pair for k-pair K2 = c*8+lg*2+b (q=lr)
        // needer word m of fragment kk2: K2 = kk2*16+lg*4+m
        unsigned int wpk[4][2];
        #pragma unroll
        for (int c = 0; c < 4; ++c) {
            wpk[c][0] = cvtpk(s[c][0], s[c][1]);
            wpk[c][1] = cvtpk(s[c][2], s[c][3]);
        }
        bf16x8 paf[2];
        #pragma unroll
        for (int kk2 = 0; kk2 < 2; ++kk2) {
            uint4v u;
            #pragma unroll
            for (int bb = 0; bb < 2; ++bb) {
                unsigned int A = wpk[2 * kk2][bb];
                unsigned int B = wpk[2 * kk2 + 1][bb];
                asm("v_permlane32_swap_b32 %0, %1" : "+v"(A), "+v"(B));
                asm("v_permlane16_swap_b32 %0, %1" : "+v"(A), "+v"(B));
                u[bb] = A;       // word m = bb
                u[2 + bb] = B;   // word m = 2+bb
            }
            paf[kk2] = __builtin_bit_cast(bf16x8, u);
        }
        // ---- O^T += V^T P^T from vt[cur] ----
        const unsigned short* vtc = &vt[cur][0];
        __builtin_amdgcn_s_setprio(1);
        #pragma unroll
        for (int kk2 = 0; kk2 < 2; ++kk2) {
            #pragma unroll
            for (int d0 = 0; d0 < 8; ++d0) {
                int rv = d0 * 16 + lr;
                bf16x8 vf = ldbf8(&vtc[rv * 64 + (((kk2 * 4 + lg) ^ (rv & 7)) << 3)]);
                o[d0] = MFMA16(vf, paf[kk2], o[d0]);
            }
        }
        __builtin_amdgcn_s_setprio(0);
        SCHED0();
        asm volatile("s_waitcnt vmcnt(0)" ::: "memory");  // next K,V landed
        BAR();
    }
    // write unnormalized partials: po[n=q0+lr][d], d = d0*16+lg*4+i consecutive
    const size_t pbase = (size_t)(b * SPLIT + sidx) * NN + q0;
    #pragma unroll
    for (int d0 = 0; d0 < 8; ++d0)
        *reinterpret_cast<f32x4*>(&po[(pbase + lr) * NCP + d0 * 16 + lg * 4]) = o[d0];
    if (lane < 16) {
        mbuf[pbase + lr] = m_i;
        lbuf[pbase + lr] = l_i;
    }
}

// ---------------- merge partials -> pt (bf16) ----------------
__global__ __launch_bounds__(256) void merge_kernel(
    const float* __restrict__ po, const float* __restrict__ mbuf,
    const float* __restrict__ lbuf, unsigned short* __restrict__ pt)
{
    const int b = blockIdx.y;
    const int n = blockIdx.x * 4 + (threadIdx.x >> 6);
    const int lane = threadIdx.x & 63;
    float m_s[SPLIT], l_s[SPLIT];
    float M = -INFINITY;
    #pragma unroll
    for (int s = 0; s < SPLIT; ++s) {
        m_s[s] = mbuf[(size_t)(b * SPLIT + s) * NN + n];
        l_s[s] = lbuf[(size_t)(b * SPLIT + s) * NN + n];
        M = fmaxf(M, m_s[s]);
    }
    float L = 0.f, wgt[SPLIT];
    #pragma unroll
    for (int s = 0; s < SPLIT; ++s) { wgt[s] = __expf(m_s[s] - M); L += wgt[s] * l_s[s]; }
    const float inv = 1.f / L;
    float ax = 0.f, ay = 0.f;
    #pragma unroll
    for (int s = 0; s < SPLIT; ++s) {
        const float2* row = (const float2*)(po + ((size_t)(b * SPLIT + s) * NN + n) * NCP);
        float2 v = row[lane];
        ax += wgt[s] * v.x;
        ay += wgt[s] * v.y;
    }
    unsigned short* dst = pt + ((size_t)b * NN + n) * NCP + lane * 2;
    dst[0] = f2bf(ax * inv);
    dst[1] = f2bf(ay * inv);
}

// ---------------- aug via MFMA: out[b][k][n] = cam + sum_d ct[b][k][d]*pt[b][n][d] ----
__global__ __launch_bounds__(256) void aug_kernel(
    const float* __restrict__ cam, const float* __restrict__ ct,
    const unsigned short* __restrict__ pt, float* __restrict__ out)
{
    const int b = blockIdx.y;
    const int tid = threadIdx.x, wid = tid >> 6, lane = tid & 63;
    const int lg = lane >> 4, lr = lane & 15;
    const int n0 = blockIdx.x * 64 + wid * 16;
    const unsigned short* ptb = pt + (size_t)b * NN * NCP;
    const float* ctb = ct + (size_t)b * NK * NCP;

    f32x4 acc[2];
    acc[0] = (f32x4){0.f, 0.f, 0.f, 0.f};
    acc[1] = (f32x4){0.f, 0.f, 0.f, 0.f};
    #pragma unroll
    for (int kk = 0; kk < 4; ++kk) {
        bf16x8 af = ldbf8(&ptb[(size_t)(n0 + lr) * NCP + kk * 32 + lg * 8]);
        #pragma unroll
        for (int c = 0; c < 2; ++c) {
            int k = c * 16 + lr;
            short8 bv;
            if (k < NK) {
                const float* cr = &ctb[(size_t)k * NCP + kk * 32 + lg * 8];
                #pragma unroll
                for (int j = 0; j < 8; ++j) bv[j] = (short)f2bf(cr[j]);
            } else {
                #pragma unroll
                for (int j = 0; j < 8; ++j) bv[j] = 0;
            }
            acc[c] = MFMA16(af, __builtin_bit_cast(bf16x8, bv), acc[c]);
        }
    }
    #pragma unroll
    for (int c = 0; c < 2; ++c) {
        int k = c * 16 + lr;
        if (k < NK) {
            #pragma unroll
            for (int i = 0; i < 4; ++i) {
                size_t off = ((size_t)b * NK + k) * NN + n0 + lg * 4 + i;
                out[off] = cam[off] + acc[c][i];
            }
        }
    }
}

extern "C" void kernel_launch(void* const* d_in, const int* in_sizes, int n_in,
                              void* d_out, int out_size, void* d_ws, size_t ws_size,
                              hipStream_t stream) {
    const float* feat = (const float*)d_in[0];
    const float* cam  = (const float*)d_in[1];
    const float* wpr  = (const float*)d_in[2];
    const float* bpr  = (const float*)d_in[3];
    float* out = (float*)d_out;

    const size_t MB = 1024 * 1024;
    char* ws = (char*)d_ws;
    unsigned short* fp  = (unsigned short*)(ws);             // 4 MB
    unsigned short* fpT = (unsigned short*)(ws + 4 * MB);    // 4 MB
    unsigned short* pt  = (unsigned short*)(ws + 8 * MB);    // 4 MB
    float* ct           = (float*)(ws + 12 * MB);            // 40 KB
    float* po           = (float*)(ws + 13 * MB);            // 32 MB fp32 partial O
    float* mbuf         = (float*)(ws + 45 * MB);            // 256 KB
    float* lbuf         = (float*)(ws + 46 * MB);            // 256 KB

    hipMemsetAsync(ct, 0, (size_t)NB * NK * NCP * sizeof(float), stream);
    proj_kernel<<<dim3(NN / 64, NB), 256, 0, stream>>>(feat, wpr, bpr, fp, fpT);
    ct_kernel<<<NB * NK * 16, 128, 0, stream>>>(cam, fp, ct);
    attn_partial_kernel<<<dim3(NN / 128, SPLIT, NB), 512, 0, stream>>>(fp, fpT, po, mbuf, lbuf);
    merge_kernel<<<dim3(NN / 4, NB), 256, 0, stream>>>(po, mbuf, lbuf, pt);
    aug_kernel<<<dim3(NN / 64, NB), 256, 0, stream>>>(cam, ct, pt, out);
}

// Round 6
// 94.826 us; speedup vs baseline: 4.6554x; 1.1128x over previous
//
#include <hip/hip_runtime.h>
#include <hip/hip_bf16.h>
#include <math.h>

#define NB 4
#define NC 512
#define NN 4096
#define NK 20
#define NCP 128
#define SPLIT 4
#define CHUNK (NN / SPLIT)   // 1024 keys per split
#define NTILES (CHUNK / 64)  // 16

typedef __bf16 bf16x8 __attribute__((ext_vector_type(8)));
typedef float f32x4 __attribute__((ext_vector_type(4)));
typedef float f32x16 __attribute__((ext_vector_type(16)));
typedef short short8 __attribute__((ext_vector_type(8)));
typedef unsigned int uint4v __attribute__((ext_vector_type(4)));

static __device__ __forceinline__ unsigned short f2bf(float f) {
    unsigned int u = __builtin_bit_cast(unsigned int, f);
    unsigned int r = (u + 0x7FFFu + ((u >> 16) & 1u)) >> 16;
    return (unsigned short)r;
}
static __device__ __forceinline__ float bf2f(unsigned short h) {
    unsigned int u = ((unsigned int)h) << 16;
    return __builtin_bit_cast(float, u);
}
static __device__ __forceinline__ bf16x8 ldbf8(const unsigned short* p) {
    return __builtin_bit_cast(bf16x8, *reinterpret_cast<const short8*>(p));
}
static __device__ __forceinline__ void gld16(const unsigned short* g, unsigned short* l) {
    __builtin_amdgcn_global_load_lds(
        (const __attribute__((address_space(1))) unsigned int*)g,
        (__attribute__((address_space(3))) unsigned int*)l, 16, 0, 0);
}
static __device__ __forceinline__ unsigned int cvtpk(float lo, float hi) {
    unsigned int r;
    asm("v_cvt_pk_bf16_f32 %0, %1, %2" : "=v"(r) : "v"(lo), "v"(hi));
    return r;
}

#define MFMA16(a, b, c) __builtin_amdgcn_mfma_f32_16x16x32_bf16(a, b, c, 0, 0, 0)
#define MFMA32(a, b, c) __builtin_amdgcn_mfma_f32_32x32x16_bf16(a, b, c, 0, 0, 0)
#define SCHED0() __builtin_amdgcn_sched_barrier(0)
#define BAR() do { SCHED0(); __builtin_amdgcn_s_barrier(); SCHED0(); } while (0)

// ---------------- wconv: fp32 w -> bf16 wb ----------------
__global__ __launch_bounds__(256) void wconv_kernel(
    const float* __restrict__ w, unsigned short* __restrict__ wb)
{
    int i = blockIdx.x * 256 + threadIdx.x;   // 16384 float4s
    float4 v = reinterpret_cast<const float4*>(w)[i];
    unsigned int lo = (unsigned int)f2bf(v.x) | ((unsigned int)f2bf(v.y) << 16);
    unsigned int hi = (unsigned int)f2bf(v.z) | ((unsigned int)f2bf(v.w) << 16);
    reinterpret_cast<uint2*>(wb)[i] = make_uint2(lo, hi);
}

// ---------------- proj: fp[b][n][d] = sum_c feat[b][c][n]*w[d][c] + bias[d] ----
__global__ __launch_bounds__(256) void proj_kernel(
    const float* __restrict__ feat, const unsigned short* __restrict__ wb,
    const float* __restrict__ bias, unsigned short* __restrict__ fp,
    unsigned short* __restrict__ fpT)
{
    const int b = blockIdx.y;
    const int n0 = blockIdx.x * 64;
    const int tid = threadIdx.x;
    const int wid = tid >> 6;
    const int lane = tid & 63;
    const int lg = lane >> 4, lr = lane & 15;

    __shared__ unsigned short lds_f[2][64][40];   // dbuf [n][c] bf16, +8 pad

    const float* featb = feat + (size_t)b * NC * NN;

    f32x4 acc[2][4];
    #pragma unroll
    for (int i = 0; i < 2; ++i)
        #pragma unroll
        for (int j = 0; j < 4; ++j) acc[i][j] = (f32x4){0.f, 0.f, 0.f, 0.f};

    float4 pre[2];
    #pragma unroll
    for (int it = 0; it < 2; ++it) {
        int idx = it * 256 + tid;
        int cc = idx >> 4, q = idx & 15;
        pre[it] = *reinterpret_cast<const float4*>(&featb[(size_t)cc * NN + n0 + q * 4]);
    }

    for (int c0 = 0; c0 < NC; c0 += 32) {
        const int cur = (c0 >> 5) & 1;
        #pragma unroll
        for (int it = 0; it < 2; ++it) {
            int idx = it * 256 + tid;
            int cc = idx >> 4, q = idx & 15;
            float4 v = pre[it];
            lds_f[cur][q * 4 + 0][cc] = f2bf(v.x);
            lds_f[cur][q * 4 + 1][cc] = f2bf(v.y);
            lds_f[cur][q * 4 + 2][cc] = f2bf(v.z);
            lds_f[cur][q * 4 + 3][cc] = f2bf(v.w);
        }
        __syncthreads();
        if (c0 + 32 < NC) {
            #pragma unroll
            for (int it = 0; it < 2; ++it) {
                int idx = it * 256 + tid;
                int cc = idx >> 4, q = idx & 15;
                pre[it] = *reinterpret_cast<const float4*>(
                    &featb[(size_t)(c0 + 32 + cc) * NN + n0 + q * 4]);
            }
        }
        bf16x8 afr[2];
        #pragma unroll
        for (int dt = 0; dt < 2; ++dt)
            afr[dt] = ldbf8(&wb[(size_t)(wid * 32 + dt * 16 + lr) * NC + c0 + lg * 8]);
        #pragma unroll
        for (int n1 = 0; n1 < 4; ++n1) {
            bf16x8 bfr = ldbf8(&lds_f[cur][n1 * 16 + lr][lg * 8]);
            #pragma unroll
            for (int dt = 0; dt < 2; ++dt)
                acc[dt][n1] = MFMA16(afr[dt], bfr, acc[dt][n1]);
        }
    }
    #pragma unroll
    for (int dt = 0; dt < 2; ++dt)
        #pragma unroll
        for (int n1 = 0; n1 < 4; ++n1)
            #pragma unroll
            for (int i = 0; i < 4; ++i) {
                int d = wid * 32 + dt * 16 + lg * 4 + i;
                int n = n0 + n1 * 16 + lr;
                unsigned short h = f2bf(acc[dt][n1][i] + bias[d]);
                fp[((size_t)b * NN + n) * NCP + d] = h;
                fpT[((size_t)b * NCP + d) * NN + n] = h;
            }
}

// ---------------- class_term: ct[b][k][d] = sum_n cam[b][k][n]*fp[b][n][d] ----
__global__ __launch_bounds__(128) void ct_kernel(
    const float* __restrict__ cam, const unsigned short* __restrict__ fp,
    float* __restrict__ ct)
{
    const int bid = blockIdx.x;
    const int chunk = bid & 15;
    const int bk = bid >> 4;
    const int b = bk / NK, k = bk % NK;
    const int d2 = threadIdx.x & 63;
    const int half = threadIdx.x >> 6;
    const int nbase = chunk * 256 + half * 128;
    const float* camp = cam + ((size_t)b * NK + k) * NN + nbase;
    const unsigned short* fpp = fp + ((size_t)b * NN + nbase) * NCP + d2 * 2;
    float ax = 0.f, ay = 0.f;
    #pragma unroll 8
    for (int n = 0; n < 128; ++n) {
        float c = camp[n];
        unsigned int v = *reinterpret_cast<const unsigned int*>(&fpp[(size_t)n * NCP]);
        ax += c * bf2f((unsigned short)(v & 0xffff));
        ay += c * bf2f((unsigned short)(v >> 16));
    }
    float* ctp = &ct[((size_t)b * NK + k) * NCP + d2 * 2];
    atomicAdd(ctp, ax);
    atomicAdd(ctp + 1, ay);
}

// ---------------- attention partials over a 1024-key chunk ----------------
// 256 threads = 4 waves; wave owns 32 q-rows; 32x32x16 MFMA.
// Swapped QK^T: S^T = K·Q^T, lane owns q=lane&31. P exchange via 8 permlane32.
__global__ __launch_bounds__(256, 2) void attn_partial_kernel(
    const unsigned short* __restrict__ fp, const unsigned short* __restrict__ fpT,
    unsigned short* __restrict__ po, float* __restrict__ mbuf, float* __restrict__ lbuf)
{
    const int b = blockIdx.z;
    const int sidx = blockIdx.y;
    const int tid = threadIdx.x;
    const int wid = tid >> 6;
    const int lane = tid & 63;
    const int l31 = lane & 31, hi = lane >> 5;
    const int q0 = blockIdx.x * 128 + wid * 32;
    const int kvbase = sidx * CHUNK;

    __shared__ unsigned short kt[2][64 * 128];   // K dbuf: [kv][d], 16-chunk XOR (rk&15)
    __shared__ unsigned short vt[2][64 * 128];   // V dbuf: pair-rows [d>>1][256B], XOR (rowp&15)

    const unsigned short* fpb  = fp  + (size_t)b * NN * NCP;
    const unsigned short* fpTb = fpT + (size_t)b * NCP * NN;

    // staging offsets: 4 K chunks + 4 V chunks per thread (1024 x 16B each tile)
    int offK[4], offV[4];
    #pragma unroll
    for (int i = 0; i < 4; ++i) {
        int oc = i * 256 + tid;
        int rk = oc >> 4, ck = oc & 15;
        offK[i] = rk * NCP + ((ck ^ (rk & 15)) << 3);
        int rowp = oc >> 4, cv = oc & 15;
        int cg = cv ^ (rowp & 15);
        int d = rowp * 2 + (cg >> 3), kvc = cg & 7;
        offV[i] = d * NN + (kvc << 3);
    }

    // Q fragments (B operand): col q = l31, depth d = kk*16 + hi*8 + j
    bf16x8 qf[8];
    #pragma unroll
    for (int kk = 0; kk < 8; ++kk)
        qf[kk] = ldbf8(&fpb[(size_t)(q0 + l31) * NCP + kk * 16 + hi * 8]);

    f32x16 o[4];
    #pragma unroll
    for (int dt = 0; dt < 4; ++dt)
        #pragma unroll
        for (int j = 0; j < 16; ++j) o[dt][j] = 0.f;
    float m_i = -INFINITY, l_i = 0.f;

    // prologue: stage K[0], V[0]
    {
        const unsigned short* k0 = fpb + (size_t)kvbase * NCP;
        const unsigned short* v0 = fpTb + kvbase;
        #pragma unroll
        for (int i = 0; i < 4; ++i) {
            gld16(k0 + offK[i], &kt[0][(i * 256 + wid * 64) * 8]);
            gld16(v0 + offV[i], &vt[0][(i * 256 + wid * 64) * 8]);
        }
    }
    SCHED0();
    asm volatile("s_waitcnt vmcnt(0)" ::: "memory");
    BAR();

    for (int t = 0; t < NTILES; ++t) {
        const int cur = t & 1;
        // ---- issue next-tile stages ----
        {
            const int tn = (t + 1) & (NTILES - 1);
            const unsigned short* knext = fpb + (size_t)(kvbase + tn * 64) * NCP;
            const unsigned short* vnext = fpTb + kvbase + tn * 64;
            #pragma unroll
            for (int i = 0; i < 4; ++i) {
                gld16(knext + offK[i], &kt[cur ^ 1][(i * 256 + wid * 64) * 8]);
                gld16(vnext + offV[i], &vt[cur ^ 1][(i * 256 + wid * 64) * 8]);
            }
        }
        SCHED0();
        // ---- S^T = K Q^T ----
        const unsigned short* ktc = &kt[cur][0];
        f32x16 s[2];
        #pragma unroll
        for (int g = 0; g < 2; ++g)
            #pragma unroll
            for (int j = 0; j < 16; ++j) s[g][j] = 0.f;
        __builtin_amdgcn_s_setprio(1);
        #pragma unroll
        for (int kk = 0; kk < 8; ++kk) {
            #pragma unroll
            for (int g = 0; g < 2; ++g) {
                int row = g * 32 + l31;
                bf16x8 kf = ldbf8(&ktc[row * 128 + (((kk * 2 + hi) ^ (row & 15)) << 3)]);
                s[g] = MFMA32(kf, qf[kk], s[g]);
            }
        }
        __builtin_amdgcn_s_setprio(0);
        // ---- online softmax: lane owns q = l31; k = (reg&3)+8*(reg>>2)+4*hi (+32g) ----
        float pmax = s[0][0];
        #pragma unroll
        for (int g = 0; g < 2; ++g)
            #pragma unroll
            for (int j = 0; j < 16; ++j) pmax = fmaxf(pmax, s[g][j]);
        pmax = fmaxf(pmax, __shfl_xor(pmax, 32));
        if (!__all(pmax - m_i <= 8.f)) {   // defer-max (THR=8)
            float mnew = fmaxf(m_i, pmax);
            float sc = __expf(m_i - mnew);
            l_i *= sc;
            #pragma unroll
            for (int dt = 0; dt < 4; ++dt)
                #pragma unroll
                for (int j = 0; j < 16; ++j) o[dt][j] *= sc;
            m_i = mnew;
        }
        float sum = 0.f;
        #pragma unroll
        for (int g = 0; g < 2; ++g)
            #pragma unroll
            for (int j = 0; j < 16; ++j) {
                float e = __expf(s[g][j] - m_i);
                s[g][j] = e;
                sum += e;
            }
        sum += __shfl_xor(sum, 32);
        l_i += sum;
        // ---- P^T -> bf16 words -> register exchange (8 permlane32_swap) ----
        // word m of group g: kv pair k = (m&1)*2 + 8*(m>>1) + 4*hi (+32g)
        unsigned int wk[2][8];
        #pragma unroll
        for (int g = 0; g < 2; ++g)
            #pragma unroll
            for (int m = 0; m < 8; ++m)
                wk[g][m] = cvtpk(s[g][2 * m], s[g][2 * m + 1]);
        bf16x8 pf[4];
        #pragma unroll
        for (int g = 0; g < 2; ++g)
            #pragma unroll
            for (int sub = 0; sub < 2; ++sub) {
                unsigned int A0 = wk[g][4 * sub],     B0 = wk[g][4 * sub + 2];
                unsigned int A1 = wk[g][4 * sub + 1], B1 = wk[g][4 * sub + 3];
                asm("v_permlane32_swap_b32 %0, %1" : "+v"(A0), "+v"(B0));
                asm("v_permlane32_swap_b32 %0, %1" : "+v"(A1), "+v"(B1));
                uint4v u;
                u[0] = A0; u[1] = A1; u[2] = B0; u[3] = B1;
                pf[2 * g + sub] = __builtin_bit_cast(bf16x8, u);
            }
        // ---- O^T += V^T P^T ----
        const unsigned short* vtc = &vt[cur][0];
        __builtin_amdgcn_s_setprio(1);
        #pragma unroll
        for (int c2 = 0; c2 < 4; ++c2) {
            #pragma unroll
            for (int dt = 0; dt < 4; ++dt) {
                int row32 = dt * 32 + l31;
                int rowp = row32 >> 1;
                int chunk = (row32 & 1) * 8 + c2 * 2 + hi;
                bf16x8 vf = ldbf8(&vtc[rowp * 128 + ((chunk ^ (rowp & 15)) << 3)]);
                o[dt] = MFMA32(vf, pf[c2], o[dt]);
            }
        }
        __builtin_amdgcn_s_setprio(0);
        SCHED0();
        asm volatile("s_waitcnt vmcnt(0)" ::: "memory");
        BAR();
    }
    // write unnormalized partials (bf16): d = dt*32 + qd*8 + 4*hi + {0..3}
    const size_t pbase = (size_t)(b * SPLIT + sidx) * NN + q0;
    const size_t rowoff = (pbase + l31) * NCP;
    #pragma unroll
    for (int dt = 0; dt < 4; ++dt)
        #pragma unroll
        for (int qd = 0; qd < 4; ++qd) {
            unsigned int u0 = cvtpk(o[dt][qd * 4 + 0], o[dt][qd * 4 + 1]);
            unsigned int u1 = cvtpk(o[dt][qd * 4 + 2], o[dt][qd * 4 + 3]);
            *reinterpret_cast<uint2*>(&po[rowoff + dt * 32 + qd * 8 + hi * 4]) =
                make_uint2(u0, u1);
        }
    if (hi == 0) {
        mbuf[pbase + l31] = m_i;
        lbuf[pbase + l31] = l_i;
    }
}

// ---------------- merge partials -> pt (bf16) ----------------
__global__ __launch_bounds__(256) void merge_kernel(
    const unsigned short* __restrict__ po, const float* __restrict__ mbuf,
    const float* __restrict__ lbuf, unsigned short* __restrict__ pt)
{
    const int b = blockIdx.y;
    const int n = blockIdx.x * 4 + (threadIdx.x >> 6);
    const int lane = threadIdx.x & 63;
    float m_s[SPLIT], l_s[SPLIT];
    float M = -INFINITY;
    #pragma unroll
    for (int s = 0; s < SPLIT; ++s) {
        m_s[s] = mbuf[(size_t)(b * SPLIT + s) * NN + n];
        l_s[s] = lbuf[(size_t)(b * SPLIT + s) * NN + n];
        M = fmaxf(M, m_s[s]);
    }
    float L = 0.f, wgt[SPLIT];
    #pragma unroll
    for (int s = 0; s < SPLIT; ++s) { wgt[s] = __expf(m_s[s] - M); L += wgt[s] * l_s[s]; }
    const float inv = 1.f / L;
    float ax = 0.f, ay = 0.f;
    #pragma unroll
    for (int s = 0; s < SPLIT; ++s) {
        unsigned int v = *reinterpret_cast<const unsigned int*>(
            &po[((size_t)(b * SPLIT + s) * NN + n) * NCP + lane * 2]);
        ax += wgt[s] * bf2f((unsigned short)(v & 0xffff));
        ay += wgt[s] * bf2f((unsigned short)(v >> 16));
    }
    unsigned int outw = (unsigned int)f2bf(ax * inv) | ((unsigned int)f2bf(ay * inv) << 16);
    *reinterpret_cast<unsigned int*>(&pt[((size_t)b * NN + n) * NCP + lane * 2]) = outw;
}

// ---------------- aug via MFMA: out[b][k][n] = cam + sum_d ct[b][k][d]*pt[b][n][d] ----
__global__ __launch_bounds__(256) void aug_kernel(
    const float* __restrict__ cam, const float* __restrict__ ct,
    const unsigned short* __restrict__ pt, float* __restrict__ out)
{
    const int b = blockIdx.y;
    const int tid = threadIdx.x, wid = tid >> 6, lane = tid & 63;
    const int lg = lane >> 4, lr = lane & 15;
    const int n0 = blockIdx.x * 64 + wid * 16;
    const unsigned short* ptb = pt + (size_t)b * NN * NCP;
    const float* ctb = ct + (size_t)b * NK * NCP;

    f32x4 acc[2];
    acc[0] = (f32x4){0.f, 0.f, 0.f, 0.f};
    acc[1] = (f32x4){0.f, 0.f, 0.f, 0.f};
    #pragma unroll
    for (int kk = 0; kk < 4; ++kk) {
        bf16x8 af = ldbf8(&ptb[(size_t)(n0 + lr) * NCP + kk * 32 + lg * 8]);
        #pragma unroll
        for (int c = 0; c < 2; ++c) {
            int k = c * 16 + lr;
            short8 bv;
            if (k < NK) {
                const float* cr = &ctb[(size_t)k * NCP + kk * 32 + lg * 8];
                #pragma unroll
                for (int j = 0; j < 8; ++j) bv[j] = (short)f2bf(cr[j]);
            } else {
                #pragma unroll
                for (int j = 0; j < 8; ++j) bv[j] = 0;
            }
            acc[c] = MFMA16(af, __builtin_bit_cast(bf16x8, bv), acc[c]);
        }
    }
    #pragma unroll
    for (int c = 0; c < 2; ++c) {
        int k = c * 16 + lr;
        if (k < NK) {
            #pragma unroll
            for (int i = 0; i < 4; ++i) {
                size_t off = ((size_t)b * NK + k) * NN + n0 + lg * 4 + i;
                out[off] = cam[off] + acc[c][i];
            }
        }
    }
}

extern "C" void kernel_launch(void* const* d_in, const int* in_sizes, int n_in,
                              void* d_out, int out_size, void* d_ws, size_t ws_size,
                              hipStream_t stream) {
    const float* feat = (const float*)d_in[0];
    const float* cam  = (const float*)d_in[1];
    const float* wpr  = (const float*)d_in[2];
    const float* bpr  = (const float*)d_in[3];
    float* out = (float*)d_out;

    const size_t MB = 1024 * 1024;
    char* ws = (char*)d_ws;
    unsigned short* fp  = (unsigned short*)(ws);                 // 4 MB
    unsigned short* fpT = (unsigned short*)(ws + 4 * MB);        // 4 MB
    unsigned short* pt  = (unsigned short*)(ws + 8 * MB);        // 4 MB
    float* ct           = (float*)(ws + 12 * MB);                // 40 KB
    unsigned short* wb  = (unsigned short*)(ws + 12 * MB + 512 * 1024); // 128 KB
    unsigned short* po  = (unsigned short*)(ws + 13 * MB);       // 16 MB bf16 partial O
    float* mbuf         = (float*)(ws + 30 * MB);                // 256 KB
    float* lbuf         = (float*)(ws + 31 * MB);                // 256 KB

    hipMemsetAsync(ct, 0, (size_t)NB * NK * NCP * sizeof(float), stream);
    wconv_kernel<<<64, 256, 0, stream>>>(wpr, wb);
    proj_kernel<<<dim3(NN / 64, NB), 256, 0, stream>>>(feat, wb, bpr, fp, fpT);
    ct_kernel<<<NB * NK * 16, 128, 0, stream>>>(cam, fp, ct);
    attn_partial_kernel<<<dim3(NN / 128, SPLIT, NB), 256, 0, stream>>>(fp, fpT, po, mbuf, lbuf);
    merge_kernel<<<dim3(NN / 4, NB), 256, 0, stream>>>(po, mbuf, lbuf, pt);
    aug_kernel<<<dim3(NN / 64, NB), 256, 0, stream>>>(cam, ct, pt, out);
}